// Round 1
// baseline (450.138 us; speedup 1.0000x reference)
//
#include <hip/hip_runtime.h>

#define NBINS 229
#define OUTF  88
#define MODEL 128
#define WSZ   30
#define WIN   61
#define TLEN  1024
#define BT    4096

__device__ __forceinline__ float tanh_fast(float x) {
    float e = __expf(2.f * x);
    return 1.f - 2.f / (e + 1.f);
}
__device__ __forceinline__ float sigmoid_f(float x) {
    return 1.f / (1.f + __expf(-x));
}

// ---------------------------------------------------------------------------
// K1: spec[BT,229] @ six weight blocks -> feat_pred(out), h_o, P_o, P_c, R, Q
// Column map (648 total):
//   [  0, 88)  W_frame            -> feat_pred (+b_frame)
//   [ 88,216)  W_attn_o rows 0..228   -> h_o
//   [216,344)  W_attn_o rows 229..457 -> P_o
//   [344,472)  W_attn_c rows 176..404 -> P_c
//   [472,560)  W_lin1             -> R
//   [560,648)  W_linc rows 176..404   -> Q
// ---------------------------------------------------------------------------
#define K1_ROWS 16

__global__ __launch_bounds__(256) void k1_gemm(
    const float* __restrict__ spec,
    const float* __restrict__ Wf,  const float* __restrict__ bf,
    const float* __restrict__ Wao, const float* __restrict__ Wac,
    const float* __restrict__ Wl1, const float* __restrict__ Wlc,
    float* __restrict__ feat, float* __restrict__ h_o,
    float* __restrict__ P_o,  float* __restrict__ P_c,
    float* __restrict__ R,    float* __restrict__ Q)
{
    __shared__ float s_spec[K1_ROWS * NBINS];
    const int s0 = blockIdx.x * K1_ROWS;
    for (int i = threadIdx.x; i < K1_ROWS * NBINS; i += 256)
        s_spec[i] = spec[(size_t)s0 * NBINS + i];
    __syncthreads();

    for (int c = threadIdx.x; c < 648; c += 256) {
        const float* p; int ld, dw, jj; float* dst; float bias = 0.f;
        if (c < 88)       { jj = c;       p = Wf  + jj;               ld = 88;    dst = feat; dw = 88;    bias = bf[jj]; }
        else if (c < 216) { jj = c - 88;  p = Wao + jj;               ld = MODEL; dst = h_o;  dw = MODEL; }
        else if (c < 344) { jj = c - 216; p = Wao + NBINS * MODEL + jj; ld = MODEL; dst = P_o; dw = MODEL; }
        else if (c < 472) { jj = c - 344; p = Wac + 176 * MODEL + jj; ld = MODEL; dst = P_c;  dw = MODEL; }
        else if (c < 560) { jj = c - 472; p = Wl1 + jj;               ld = 88;    dst = R;    dw = 88; }
        else              { jj = c - 560; p = Wlc + 176 * 88 + jj;    ld = 88;    dst = Q;    dw = 88; }

        float acc[K1_ROWS];
#pragma unroll
        for (int r = 0; r < K1_ROWS; r++) acc[r] = 0.f;
        for (int k = 0; k < NBINS; k++) {
            float w = p[(size_t)k * ld];
#pragma unroll
            for (int r = 0; r < K1_ROWS; r++) acc[r] += s_spec[r * NBINS + k] * w;
        }
#pragma unroll
        for (int r = 0; r < K1_ROWS; r++)
            dst[(size_t)(s0 + r) * dw + jj] = acc[r] + bias;
    }
}

// ---------------------------------------------------------------------------
// K3: x[BT,176] @ [W_attn_c rows 0..175 | W_linc rows 0..175] -> h_c, linx
// ---------------------------------------------------------------------------
__global__ __launch_bounds__(256) void k3_gemm(
    const float* __restrict__ x,
    const float* __restrict__ Wac, const float* __restrict__ Wlc,
    float* __restrict__ h_c, float* __restrict__ linx)
{
    __shared__ float s_x[K1_ROWS * 176];
    const int s0 = blockIdx.x * K1_ROWS;
    for (int i = threadIdx.x; i < K1_ROWS * 176; i += 256)
        s_x[i] = x[(size_t)s0 * 176 + i];
    __syncthreads();

    int c = threadIdx.x;
    if (c >= 216) return;
    const float* p; int ld, dw, jj; float* dst;
    if (c < 128) { jj = c;       p = Wac + jj; ld = MODEL; dst = h_c;  dw = MODEL; }
    else         { jj = c - 128; p = Wlc + jj; ld = 88;    dst = linx; dw = 88; }

    float acc[K1_ROWS];
#pragma unroll
    for (int r = 0; r < K1_ROWS; r++) acc[r] = 0.f;
    for (int k = 0; k < 176; k++) {
        float w = p[(size_t)k * ld];
#pragma unroll
        for (int r = 0; r < K1_ROWS; r++) acc[r] += s_x[r * 176 + k] * w;
    }
#pragma unroll
    for (int r = 0; r < K1_ROWS; r++)
        dst[(size_t)(s0 + r) * dw + jj] = acc[r];
}

// ---------------------------------------------------------------------------
// Attention kernel (used for both onset and combine stacks).
// One block (256 threads) per position s in [0, BT).
//   score[w] = sum_d tanh(h[s][d] + bvec[d] + P[s+w-30][d]) * vvec[d]
//   (out-of-range windows: P contribution = 0, still in softmax)
//   a = softmax(score) -> a_out
//   pred = sigmoid(pred_bias + base[s] + sum_w a[w]*RQ[s+w-30]) -> pred_out
//   if x_out: x_out[s] = [feat[s], pred]   (for the combine-stack GEMM)
// ---------------------------------------------------------------------------
__global__ __launch_bounds__(256) void attn_kernel(
    const float* __restrict__ h_all, const float* __restrict__ P_all,
    const float* __restrict__ bvec,  const float* __restrict__ vvec,
    const float* __restrict__ RQ,    const float* __restrict__ pred_bias,
    const float* __restrict__ base,  const float* __restrict__ feat,
    float* __restrict__ a_out, float* __restrict__ pred_out,
    float* __restrict__ x_out)
{
    const int s  = blockIdx.x;
    const int tt = s & (TLEN - 1);
    const int tid = threadIdx.x;

    __shared__ float hb[MODEL];
    __shared__ float sc[WIN + 3];
    __shared__ float red[4];
    __shared__ float aw[WIN + 3];

    if (tid < MODEL) hb[tid] = h_all[(size_t)s * MODEL + tid] + bvec[tid];
    __syncthreads();

    const int d  = tid & (MODEL - 1);
    const int wh = tid >> 7;          // 0 or 1: which window of the pair
    const float vd = vvec[d];

    for (int wb = 0; wb < WIN + 1; wb += 2) {
        int w = wb + wh;
        float e = 0.f;
        if (w < WIN) {
            int ts = tt + w - WSZ;
            float pv = 0.f;
            if ((unsigned)ts < TLEN)
                pv = P_all[(size_t)(s + w - WSZ) * MODEL + d];
            e = tanh_fast(hb[d] + pv) * vd;
        }
#pragma unroll
        for (int m = 32; m; m >>= 1) e += __shfl_xor(e, m, 64);
        if ((tid & 63) == 0) red[tid >> 6] = e;
        __syncthreads();
        if (tid == 0)                            sc[wb]     = red[0] + red[1];
        else if (tid == 128 && wb + 1 < WIN)     sc[wb + 1] = red[2] + red[3];
        __syncthreads();
    }

    // softmax over 61 scores (wave 0)
    if (tid < 64) {
        float v = (tid < WIN) ? sc[tid] : -1e30f;
        float mx = v;
#pragma unroll
        for (int m = 32; m; m >>= 1) mx = fmaxf(mx, __shfl_xor(mx, m, 64));
        float ex = (tid < WIN) ? __expf(v - mx) : 0.f;
        float sm = ex;
#pragma unroll
        for (int m = 32; m; m >>= 1) sm += __shfl_xor(sm, m, 64);
        float a = ex / sm;
        if (tid < WIN) {
            aw[tid] = a;
            a_out[(size_t)s * WIN + tid] = a;
        }
    }
    __syncthreads();

    if (tid < OUTF) {
        float acc = pred_bias[tid];
        if (base) acc += base[(size_t)s * OUTF + tid];
        for (int w = 0; w < WIN; w++) {
            int ts = tt + w - WSZ;
            if ((unsigned)ts < TLEN)
                acc += aw[w] * RQ[(size_t)(s + w - WSZ) * OUTF + tid];
        }
        float p = sigmoid_f(acc);
        pred_out[(size_t)s * OUTF + tid] = p;
        if (x_out) {
            x_out[(size_t)s * 176 + OUTF + tid] = p;
            x_out[(size_t)s * 176 + tid]        = feat[(size_t)s * OUTF + tid];
        }
    }
}

// ---------------------------------------------------------------------------
extern "C" void kernel_launch(void* const* d_in, const int* in_sizes, int n_in,
                              void* d_out, int out_size, void* d_ws, size_t ws_size,
                              hipStream_t stream)
{
    const float* spec = (const float*)d_in[0];
    const float* Wf   = (const float*)d_in[1];
    const float* bf   = (const float*)d_in[2];
    const float* Wao  = (const float*)d_in[3];
    const float* bao  = (const float*)d_in[4];
    const float* vo   = (const float*)d_in[5];
    const float* Wl1  = (const float*)d_in[6];
    const float* bl1  = (const float*)d_in[7];
    const float* Wac  = (const float*)d_in[8];
    const float* bac  = (const float*)d_in[9];
    const float* vc   = (const float*)d_in[10];
    const float* Wlc  = (const float*)d_in[11];
    const float* blc  = (const float*)d_in[12];

    float* out  = (float*)d_out;
    float* out0 = out;                 // frame_pred [BT,88]
    float* out1 = out + 360448;        // a_frame    [BT,61]
    float* out2 = out + 610304;        // onset_pred [BT,88]
    float* out3 = out + 970752;        // a_onset    [BT,61]
    float* out4 = out + 1220608;       // feat_pred  [BT,88]

    float* ws  = (float*)d_ws;
    float* h_o = ws;                   // [BT,128]
    float* P_o = ws + 524288;          // [BT,128]
    float* P_c = ws + 1048576;         // [BT,128]
    float* Rm  = ws + 1572864;         // [BT,88]
    float* Qm  = ws + 1933312;         // [BT,88]
    float* xm  = ws + 2293760;         // [BT,176]
    float* h_c = ws + 3014656;         // [BT,128]
    float* lnx = ws + 3538944;         // [BT,88]
    (void)ws_size; (void)in_sizes; (void)n_in; (void)out_size;

    k1_gemm<<<BT / K1_ROWS, 256, 0, stream>>>(spec, Wf, bf, Wao, Wac, Wl1, Wlc,
                                              out4, h_o, P_o, P_c, Rm, Qm);
    attn_kernel<<<BT, 256, 0, stream>>>(h_o, P_o, bao, vo, Rm, bl1,
                                        nullptr, out4, out3, out2, xm);
    k3_gemm<<<BT / K1_ROWS, 256, 0, stream>>>(xm, Wac, Wlc, h_c, lnx);
    attn_kernel<<<BT, 256, 0, stream>>>(h_c, P_c, bac, vc, Qm, blc,
                                        lnx, nullptr, out1, out0, nullptr);
}

// Round 2
// 246.236 us; speedup vs baseline: 1.8281x; 1.8281x over previous
//
#include <hip/hip_runtime.h>

#define NBINS 229
#define OUTF  88
#define MODEL 128
#define WSZ   30
#define WIN   61
#define TLEN  1024
#define BT    4096

// packed GEMM geometry
#define NP1 704      // k1 padded N (11*64); real cols 648
#define NC1 648
#define KP1 232      // k1 padded K (29*8); real K 229
#define NP2 256      // k3 padded N; real cols 216
#define NC2 216
#define KP2 176      // k3 K (22*8 exact)
#define C1LD 560     // C1 stores cols [88,648) -> stride 560

__device__ __forceinline__ float tanh_fast(float x) {
    float e = __expf(2.f * x);
    return 1.f - 2.f / (e + 1.f);
}
__device__ __forceinline__ float sigmoid_f(float x) {
    return 1.f / (1.f + __expf(-x));
}

// ---------------------------------------------------------------------------
// Pack both B matrices + bias vectors into workspace.
// B1[KP1][NP1] column map (n):
//   [  0, 88) Wf[k][n]          [ 88,216) Wao[k][n-88]
//   [216,344) Wao[k+229][n-216] [344,472) Wac[k+176][n-344]
//   [472,560) Wl1[k][n-472]     [560,648) Wlc[k+176][n-560]
// B2[KP2][NP2]: [0,128) Wac[k][n]; [128,216) Wlc[k][n-128]
// bias1[NP1]: [0,88)=bf, [88,216)=bao, else 0   (bao folded into h_o)
// bias2[NP2]: [0,128)=bac, else 0               (bac folded into h_c)
// ---------------------------------------------------------------------------
#define B1_ELEMS (KP1 * NP1)
#define B2_ELEMS (KP2 * NP2)
#define PACK_TOTAL (B1_ELEMS + B2_ELEMS + NP1 + NP2)

__global__ __launch_bounds__(256) void pack_kernel(
    const float* __restrict__ Wf,  const float* __restrict__ bf,
    const float* __restrict__ Wao, const float* __restrict__ bao,
    const float* __restrict__ Wl1,
    const float* __restrict__ Wac, const float* __restrict__ bac,
    const float* __restrict__ Wlc,
    float* __restrict__ B1, float* __restrict__ B2,
    float* __restrict__ bias1, float* __restrict__ bias2)
{
    int idx = blockIdx.x * 256 + threadIdx.x;
    if (idx >= PACK_TOTAL) return;
    if (idx < B1_ELEMS) {
        int k = idx / NP1, n = idx % NP1;
        float v = 0.f;
        if (k < NBINS && n < NC1) {
            if (n < 88)       v = Wf[k * 88 + n];
            else if (n < 216) v = Wao[k * MODEL + (n - 88)];
            else if (n < 344) v = Wao[(k + NBINS) * MODEL + (n - 216)];
            else if (n < 472) v = Wac[(k + 176) * MODEL + (n - 344)];
            else if (n < 560) v = Wl1[k * 88 + (n - 472)];
            else              v = Wlc[(k + 176) * 88 + (n - 560)];
        }
        B1[idx] = v;
    } else if (idx < B1_ELEMS + B2_ELEMS) {
        int j = idx - B1_ELEMS;
        int k = j / NP2, n = j % NP2;
        float v = 0.f;
        if (n < 128)      v = Wac[k * MODEL + n];
        else if (n < 216) v = Wlc[k * 88 + (n - 128)];
        B2[j] = v;
    } else if (idx < B1_ELEMS + B2_ELEMS + NP1) {
        int n = idx - (B1_ELEMS + B2_ELEMS);
        bias1[n] = (n < 88) ? bf[n] : (n < 216) ? bao[n - 88] : 0.f;
    } else {
        int n = idx - (B1_ELEMS + B2_ELEMS + NP1);
        bias2[n] = (n < 128) ? bac[n] : 0.f;
    }
}

// ---------------------------------------------------------------------------
// Tiled fp32 GEMM: C[M,Nc] = A[M,K] @ Bp[Kpad,Npad] (+bias[col])
// 64x64 tile, 256 threads, 4x4 micro-tile, KB=8.
// Stores cols in [cskip, Nc) to C at stride ldc (col-cskip offset);
// cols < 88 additionally to feat_out (if non-null).
// ---------------------------------------------------------------------------
#define KB 8
#define ASTR 72
#define BSTR 68

__global__ __launch_bounds__(256) void gemm_tiled(
    const float* __restrict__ A, int lda, int K, int Kpad,
    const float* __restrict__ Bp, int Npad,
    const float* __restrict__ bias,
    float* __restrict__ C, int ldc, int Nc, int cskip,
    float* __restrict__ feat_out)
{
    __shared__ float As[KB * ASTR];
    __shared__ float Bs[KB * BSTR];
    const int tid = threadIdx.x;
    const int tx = tid & 15, ty = tid >> 4;
    const int rbase = blockIdx.y * 64;
    const int cbase = blockIdx.x * 64;

    float acc[4][4];
#pragma unroll
    for (int i = 0; i < 4; i++)
#pragma unroll
        for (int j = 0; j < 4; j++) acc[i][j] = 0.f;

    const int aidx = tid * 2;
    const int ar = aidx >> 3, akk = aidx & 7;
    const int bkk = aidx >> 6, bc = aidx & 63;

    for (int k0 = 0; k0 < Kpad; k0 += KB) {
        // stage A transposed: As[kk][row]
        {
            int k = k0 + akk;
            const float* ap = A + (size_t)(rbase + ar) * lda + k;
            float a0 = (k < K) ? ap[0] : 0.f;
            float a1 = (k + 1 < K) ? ap[1] : 0.f;
            As[akk * ASTR + ar] = a0;
            As[(akk + 1) * ASTR + ar] = a1;
        }
        // stage B: Bs[kk][col]
        {
            const float2 bv = *(const float2*)&Bp[(size_t)(k0 + bkk) * Npad + cbase + bc];
            *(float2*)&Bs[bkk * BSTR + bc] = bv;
        }
        __syncthreads();
#pragma unroll
        for (int kk = 0; kk < KB; kk++) {
            float4 av = *(const float4*)&As[kk * ASTR + ty * 4];
            float4 bv = *(const float4*)&Bs[kk * BSTR + tx * 4];
            float a[4] = {av.x, av.y, av.z, av.w};
            float b[4] = {bv.x, bv.y, bv.z, bv.w};
#pragma unroll
            for (int i = 0; i < 4; i++)
#pragma unroll
                for (int j = 0; j < 4; j++) acc[i][j] += a[i] * b[j];
        }
        __syncthreads();
    }

#pragma unroll
    for (int i = 0; i < 4; i++) {
        int r = rbase + ty * 4 + i;
#pragma unroll
        for (int j = 0; j < 4; j++) {
            int c = cbase + tx * 4 + j;
            if (c < Nc) {
                float val = acc[i][j] + bias[c];
                if (c >= cskip) C[(size_t)r * ldc + (c - cskip)] = val;
                if (feat_out && c < 88) feat_out[(size_t)r * 88 + c] = val;
            }
        }
    }
}

// ---------------------------------------------------------------------------
// Attention v2: one wave per position, 4 positions per 256-thread block.
// Window rows (64) of P (128-dim, bias pre-folded into h) and RQ (88-dim)
// staged in LDS once per block. Lane = window for the energy phase (no
// reductions); in-wave butterfly softmax; lane = feature for weighted sum.
// ---------------------------------------------------------------------------
#define PSTR 140   // 140*4=560B row stride: 16B aligned, bank coeff 3 (odd-ish)
#define RSTR 92    // 368B: 16B aligned

__global__ __launch_bounds__(256) void attn_v2(
    const float* __restrict__ h_all, int hs,
    const float* __restrict__ P_all, int Ps,
    const float* __restrict__ vvec,
    const float* __restrict__ RQ, int RQs,
    const float* __restrict__ pred_bias,
    const float* __restrict__ base, int bs,
    const float* __restrict__ feat,
    float* __restrict__ a_out, float* __restrict__ pred_out,
    float* __restrict__ x_out)
{
    __shared__ float Pl[64 * PSTR];
    __shared__ float Rl[64 * RSTR];
    __shared__ float Hl[4 * 132];
    __shared__ float Vl[128];

    const int tid = threadIdx.x;
    const int s0 = blockIdx.x * 4;
    const int t0 = s0 & (TLEN - 1);

    if (tid < 128) Vl[tid] = vvec[tid];
#pragma unroll
    for (int i = tid; i < 512; i += 256) {
        int q = i >> 7, d = i & 127;
        Hl[q * 132 + d] = h_all[(size_t)(s0 + q) * hs + d];
    }
    for (int i = tid; i < 64 * 128; i += 256) {
        int j = i >> 7, d = i & 127;
        int tg = t0 + j - WSZ;
        float v = 0.f;
        if ((unsigned)tg < (unsigned)TLEN)
            v = P_all[(size_t)(s0 + j - WSZ) * Ps + d];
        Pl[j * PSTR + d] = v;
    }
    for (int i = tid; i < 64 * 88; i += 256) {
        int j = i / 88, f = i - j * 88;
        int tg = t0 + j - WSZ;
        float v = 0.f;
        if ((unsigned)tg < (unsigned)TLEN)
            v = RQ[(size_t)(s0 + j - WSZ) * RQs + f];
        Rl[j * RSTR + f] = v;
    }
    __syncthreads();

    const int q = tid >> 6;           // position within block
    const int w = tid & 63;           // lane = window index
    const int s = s0 + q;
    const int row = q + ((w < WIN) ? w : 0);

    // energy: e[w] = sum_d tanh(h[d] + P[w][d]) * v[d]
    float e = 0.f;
    const float4* Prow = (const float4*)&Pl[row * PSTR];
    const float4* Hrow = (const float4*)&Hl[q * 132];
    const float4* Vr   = (const float4*)Vl;
#pragma unroll 8
    for (int d4 = 0; d4 < 32; d4++) {
        float4 p = Prow[d4];
        float4 h = Hrow[d4];
        float4 v = Vr[d4];
        e += tanh_fast(h.x + p.x) * v.x;
        e += tanh_fast(h.y + p.y) * v.y;
        e += tanh_fast(h.z + p.z) * v.z;
        e += tanh_fast(h.w + p.w) * v.w;
    }
    if (w >= WIN) e = -1e30f;

    // in-wave softmax over 61 windows
    float mx = e;
#pragma unroll
    for (int m = 32; m; m >>= 1) mx = fmaxf(mx, __shfl_xor(mx, m, 64));
    float ex = __expf(e - mx);
    float sm = ex;
#pragma unroll
    for (int m = 32; m; m >>= 1) sm += __shfl_xor(sm, m, 64);
    float a = ex / sm;
    if (w < WIN) a_out[(size_t)s * WIN + w] = a;

    // weighted sum: lane covers features f0=w and f1=w+64 (f1 only w<24)
    float acc0 = 0.f, acc1 = 0.f;
    const int f1 = (w < 24) ? w + 64 : 64;
    for (int ww = 0; ww < WIN; ww++) {
        float aw = __shfl(a, ww, 64);
        const float* Rrow = &Rl[(q + ww) * RSTR];
        acc0 += aw * Rrow[w];
        acc1 += aw * Rrow[f1];
    }

    float o0 = pred_bias[w] + acc0;
    if (base) o0 += base[(size_t)s * bs + w];
    float p0 = sigmoid_f(o0);
    pred_out[(size_t)s * OUTF + w] = p0;
    if (x_out) {
        x_out[(size_t)s * 176 + OUTF + w] = p0;
        x_out[(size_t)s * 176 + w] = feat[(size_t)s * OUTF + w];
    }
    if (w < 24) {
        float o1 = pred_bias[w + 64] + acc1;
        if (base) o1 += base[(size_t)s * bs + w + 64];
        float p1 = sigmoid_f(o1);
        pred_out[(size_t)s * OUTF + w + 64] = p1;
        if (x_out) {
            x_out[(size_t)s * 176 + OUTF + 64 + w] = p1;
            x_out[(size_t)s * 176 + 64 + w] = feat[(size_t)s * OUTF + 64 + w];
        }
    }
}

// ---------------------------------------------------------------------------
extern "C" void kernel_launch(void* const* d_in, const int* in_sizes, int n_in,
                              void* d_out, int out_size, void* d_ws, size_t ws_size,
                              hipStream_t stream)
{
    const float* spec = (const float*)d_in[0];
    const float* Wf   = (const float*)d_in[1];
    const float* bf   = (const float*)d_in[2];
    const float* Wao  = (const float*)d_in[3];
    const float* bao  = (const float*)d_in[4];
    const float* vo   = (const float*)d_in[5];
    const float* Wl1  = (const float*)d_in[6];
    const float* bl1  = (const float*)d_in[7];
    const float* Wac  = (const float*)d_in[8];
    const float* bac  = (const float*)d_in[9];
    const float* vc   = (const float*)d_in[10];
    const float* Wlc  = (const float*)d_in[11];
    const float* blc  = (const float*)d_in[12];

    float* out  = (float*)d_out;
    float* out0 = out;                 // frame_pred [BT,88]
    float* out1 = out + 360448;        // a_frame    [BT,61]
    float* out2 = out + 610304;        // onset_pred [BT,88]
    float* out3 = out + 970752;        // a_onset    [BT,61]
    float* out4 = out + 1220608;       // feat_pred  [BT,88]

    float* ws    = (float*)d_ws;
    float* B2    = ws;                         // 45,056
    float* bias2 = ws + 45056;                 // 256
    float* B1    = ws + 45312;                 // 163,328 (dead after k1)
    float* bias1 = ws + 208640;                // 704     (dead after k1)
    float* xm    = ws + 45312;                 // 720,896 — aliases B1/bias1
    float* C1    = ws + 766208;                // 4096*560 = 2,293,760
    float* C2    = ws + 3059968;               // 4096*216 = 884,736
    (void)ws_size; (void)in_sizes; (void)n_in; (void)out_size;

    // C1 holds k1 cols [88,648) at stride 560:
    float* h_o = C1;          // +bao folded
    float* P_o = C1 + 128;
    float* P_c = C1 + 256;
    float* Rm  = C1 + 384;
    float* Qm  = C1 + 472;
    // C2: h_c (+bac folded) at 0, linx at 128, stride 216

    pack_kernel<<<(PACK_TOTAL + 255) / 256, 256, 0, stream>>>(
        Wf, bf, Wao, bao, Wl1, Wac, bac, Wlc, B1, B2, bias1, bias2);

    gemm_tiled<<<dim3(NP1 / 64, BT / 64), 256, 0, stream>>>(
        spec, NBINS, NBINS, KP1, B1, NP1, bias1, C1, C1LD, NC1, 88, out4);

    attn_v2<<<BT / 4, 256, 0, stream>>>(
        h_o, C1LD, P_o, C1LD, vo, Rm, C1LD, bl1, nullptr, 0,
        out4, out3, out2, xm);

    gemm_tiled<<<dim3(NP2 / 64, BT / 64), 256, 0, stream>>>(
        xm, 176, 176, KP2, B2, NP2, bias2, C2, NC2, NC2, 0, nullptr);

    attn_v2<<<BT / 4, 256, 0, stream>>>(
        C2, NC2, P_c, C1LD, vc, Qm, C1LD, blc, C2 + 128, NC2,
        nullptr, out1, out0, nullptr);
}

// Round 3
// 219.909 us; speedup vs baseline: 2.0469x; 1.1197x over previous
//
#include <hip/hip_runtime.h>

#define NBINS 229
#define OUTF  88
#define MODEL 128
#define WSZ   30
#define WIN   61
#define TLEN  1024
#define BT    4096

// packed GEMM geometry
#define NP1 704      // k1 padded N (11*64); real cols 648
#define NC1 648
#define KP1 240      // k1 padded K (15*16); real K 229
#define NP2 256      // k3 padded N; real cols 216
#define NC2 216
#define KP2 176      // k3 K (11*16 exact)
#define C1LD 560     // C1 stores cols [88,648) -> stride 560

__device__ __forceinline__ float tanh_fast(float x) {
    float e = __expf(2.f * x);
    return 1.f - 2.f / (e + 1.f);
}
__device__ __forceinline__ float sigmoid_f(float x) {
    return 1.f / (1.f + __expf(-x));
}

// ---------------------------------------------------------------------------
// Pack both B matrices + bias vectors into workspace.
// B1[KP1][NP1] column map (n):
//   [  0, 88) Wf[k][n]          [ 88,216) Wao[k][n-88]
//   [216,344) Wao[k+229][n-216] [344,472) Wac[k+176][n-344]
//   [472,560) Wl1[k][n-472]     [560,648) Wlc[k+176][n-560]
// B2[KP2][NP2]: [0,128) Wac[k][n]; [128,216) Wlc[k][n-128]
// bias1[NP1]: [0,88)=bf, [88,216)=bao, else 0   (bao folded into h_o)
// bias2[NP2]: [0,128)=bac, else 0               (bac folded into h_c)
// ---------------------------------------------------------------------------
#define B1_ELEMS (KP1 * NP1)
#define B2_ELEMS (KP2 * NP2)
#define PACK_TOTAL (B1_ELEMS + B2_ELEMS + NP1 + NP2)

__global__ __launch_bounds__(256) void pack_kernel(
    const float* __restrict__ Wf,  const float* __restrict__ bf,
    const float* __restrict__ Wao, const float* __restrict__ bao,
    const float* __restrict__ Wl1,
    const float* __restrict__ Wac, const float* __restrict__ bac,
    const float* __restrict__ Wlc,
    float* __restrict__ B1, float* __restrict__ B2,
    float* __restrict__ bias1, float* __restrict__ bias2)
{
    int idx = blockIdx.x * 256 + threadIdx.x;
    if (idx >= PACK_TOTAL) return;
    if (idx < B1_ELEMS) {
        int k = idx / NP1, n = idx % NP1;
        float v = 0.f;
        if (k < NBINS && n < NC1) {
            if (n < 88)       v = Wf[k * 88 + n];
            else if (n < 216) v = Wao[k * MODEL + (n - 88)];
            else if (n < 344) v = Wao[(k + NBINS) * MODEL + (n - 216)];
            else if (n < 472) v = Wac[(k + 176) * MODEL + (n - 344)];
            else if (n < 560) v = Wl1[k * 88 + (n - 472)];
            else              v = Wlc[(k + 176) * 88 + (n - 560)];
        }
        B1[idx] = v;
    } else if (idx < B1_ELEMS + B2_ELEMS) {
        int j = idx - B1_ELEMS;
        int k = j / NP2, n = j % NP2;
        float v = 0.f;
        if (n < 128)      v = Wac[k * MODEL + n];
        else if (n < 216) v = Wlc[k * 88 + (n - 128)];
        B2[j] = v;
    } else if (idx < B1_ELEMS + B2_ELEMS + NP1) {
        int n = idx - (B1_ELEMS + B2_ELEMS);
        bias1[n] = (n < 88) ? bf[n] : (n < 216) ? bao[n - 88] : 0.f;
    } else {
        int n = idx - (B1_ELEMS + B2_ELEMS + NP1);
        bias2[n] = (n < 128) ? bac[n] : 0.f;
    }
}

// ---------------------------------------------------------------------------
// LDS-tiled transpose: spec[4096,229] -> specT[240,4096] (zero-padded rows)
// ---------------------------------------------------------------------------
__global__ __launch_bounds__(256) void transpose_spec(
    const float* __restrict__ spec, float* __restrict__ specT)
{
    __shared__ float tile[32][33];
    const int k0 = blockIdx.x * 32;
    const int m0 = blockIdx.y * 32;
    const int x = threadIdx.x & 31, y4 = (threadIdx.x >> 5) * 4;
#pragma unroll
    for (int i = 0; i < 4; i++) {
        int k = k0 + x;
        tile[y4 + i][x] = (k < NBINS) ? spec[(size_t)(m0 + y4 + i) * NBINS + k] : 0.f;
    }
    __syncthreads();
#pragma unroll
    for (int i = 0; i < 4; i++) {
        int k = k0 + y4 + i;
        if (k < KP1) specT[(size_t)k * 4096 + m0 + x] = tile[x][y4 + i];
    }
}

// ---------------------------------------------------------------------------
// Tiled fp32 GEMM: C[M,Nc] = A @ Bp[Kpad,Npad] (+bias[col])
// 64x64 tile, 256 threads, 4x4 micro-tile, KB=16.
// A source: if AT != null, AT[Kpad][4096] (pre-transposed, pre-padded,
// fully coalesced staging); else row-major A[M][lda] with k<K guard.
// Stores cols in [cskip, Nc) to C at stride ldc; cols<88 also to feat_out.
// ---------------------------------------------------------------------------
#define KB 16
#define ASTR 68
#define BSTR 64

__global__ __launch_bounds__(256) void gemm_tiled(
    const float* __restrict__ A, const float* __restrict__ AT,
    int lda, int K, int Kpad,
    const float* __restrict__ Bp, int Npad,
    const float* __restrict__ bias,
    float* __restrict__ C, int ldc, int Nc, int cskip,
    float* __restrict__ feat_out)
{
    __shared__ float As[KB * ASTR];
    __shared__ float Bs[KB * BSTR];
    const int tid = threadIdx.x;
    const int tx = tid & 15, ty = tid >> 4;
    const int rbase = blockIdx.y * 64;
    const int cbase = blockIdx.x * 64;

    float acc[4][4];
#pragma unroll
    for (int i = 0; i < 4; i++)
#pragma unroll
        for (int j = 0; j < 4; j++) acc[i][j] = 0.f;

    // staging indices
    const int skk = tid >> 4;            // 0..15 (k within block)
    const int sc4 = (tid & 15) * 4;      // 0..60 (col/row group of 4)
    const int ar = tid >> 2;             // 0..63 row (row-major A path)
    const int akl = tid & 3;             // k lane

    for (int k0 = 0; k0 < Kpad; k0 += KB) {
        if (AT) {
            // coalesced: 16 lanes x 16B = one 256B row segment per kk
            float4 av = *(const float4*)&AT[(size_t)(k0 + skk) * 4096 + rbase + sc4];
            *(float4*)&As[skk * ASTR + sc4] = av;
        } else {
            const float* arow = A + (size_t)(rbase + ar) * lda;
#pragma unroll
            for (int i = 0; i < 4; i++) {
                int k = k0 + akl + 4 * i;
                As[(akl + 4 * i) * ASTR + ar] = (k < K) ? arow[k] : 0.f;
            }
        }
        {
            float4 bv = *(const float4*)&Bp[(size_t)(k0 + skk) * Npad + cbase + sc4];
            *(float4*)&Bs[skk * BSTR + sc4] = bv;
        }
        __syncthreads();
#pragma unroll
        for (int kk = 0; kk < KB; kk++) {
            float4 av = *(const float4*)&As[kk * ASTR + ty * 4];
            float4 bv = *(const float4*)&Bs[kk * BSTR + tx * 4];
            float a[4] = {av.x, av.y, av.z, av.w};
            float b[4] = {bv.x, bv.y, bv.z, bv.w};
#pragma unroll
            for (int i = 0; i < 4; i++)
#pragma unroll
                for (int j = 0; j < 4; j++) acc[i][j] += a[i] * b[j];
        }
        __syncthreads();
    }

#pragma unroll
    for (int i = 0; i < 4; i++) {
        int r = rbase + ty * 4 + i;
#pragma unroll
        for (int j = 0; j < 4; j++) {
            int c = cbase + tx * 4 + j;
            if (c < Nc) {
                float val = acc[i][j] + bias[c];
                if (c >= cskip) C[(size_t)r * ldc + (c - cskip)] = val;
                if (feat_out && c < 88) feat_out[(size_t)r * 88 + c] = val;
            }
        }
    }
}

// ---------------------------------------------------------------------------
// Attention v3: one wave per position, 8 positions per 512-thread block.
// P staged TRANSPOSED in LDS (Pl[d][j], stride 69 = odd -> conflict-free:
// energy-loop lanes read consecutive j). h (+bias folded) and v read as
// LDS broadcasts. Weighted sum reads R/Q rows directly from global
// (coalesced, L2-hot). In-wave butterfly softmax.
// ---------------------------------------------------------------------------
#define PT 69   // transposed P row stride (odd -> conflict-free)

__global__ __launch_bounds__(512) void attn_v3(
    const float* __restrict__ h_all, int hs,
    const float* __restrict__ P_all, int Ps,
    const float* __restrict__ vvec,
    const float* __restrict__ RQ, int RQs,
    const float* __restrict__ pred_bias,
    const float* __restrict__ base, int bs,
    const float* __restrict__ feat,
    float* __restrict__ a_out, float* __restrict__ pred_out,
    float* __restrict__ x_out)
{
    __shared__ float Pl[128 * PT];    // 35,328 B
    __shared__ float Hl[8 * 128];     // 4,096 B
    __shared__ float Vl[128];

    const int tid = threadIdx.x;
    const int s0 = blockIdx.x * 8;
    const int t0 = s0 & (TLEN - 1);

    if (tid < 128) Vl[tid] = vvec[tid];
    for (int i = tid; i < 8 * 128; i += 512) {
        int q = i >> 7, d = i & 127;
        Hl[i] = h_all[(size_t)(s0 + q) * hs + d];
    }
    // 68 window rows (j=0..67 <-> position s0-30+j), transposed into Pl
    for (int i = tid; i < 68 * 128; i += 512) {
        int j = i >> 7, d = i & 127;
        int tg = t0 + j - WSZ;
        float v = 0.f;
        if ((unsigned)tg < (unsigned)TLEN)
            v = P_all[(size_t)(s0 - WSZ + j) * Ps + d];
        Pl[d * PT + j] = v;
    }
    __syncthreads();

    const int q = tid >> 6;           // position within block
    const int w = tid & 63;           // lane = window index
    const int s = s0 + q;
    const int j = q + ((w < WIN) ? w : 0);
    const float4* H4 = (const float4*)(Hl + q * 128);
    const float4* V4 = (const float4*)Vl;

    float e = 0.f;
#pragma unroll 8
    for (int d4 = 0; d4 < 32; d4++) {
        float4 h = H4[d4];
        float4 v = V4[d4];
        const float* pb = &Pl[(d4 * 4) * PT + j];
        e += tanh_fast(h.x + pb[0])      * v.x;
        e += tanh_fast(h.y + pb[PT])     * v.y;
        e += tanh_fast(h.z + pb[2 * PT]) * v.z;
        e += tanh_fast(h.w + pb[3 * PT]) * v.w;
    }
    if (w >= WIN) e = -1e30f;

    // in-wave softmax over 61 windows
    float mx = e;
#pragma unroll
    for (int m = 32; m; m >>= 1) mx = fmaxf(mx, __shfl_xor(mx, m, 64));
    float ex = __expf(e - mx);
    float sm = ex;
#pragma unroll
    for (int m = 32; m; m >>= 1) sm += __shfl_xor(sm, m, 64);
    float a = ex / sm;
    if (w < WIN) a_out[(size_t)s * WIN + w] = a;

    // weighted sum: lane = feature (w and w+64); R/Q rows from global
    float acc0 = pred_bias[w];
    float acc1 = (w < 24) ? pred_bias[w + 64] : 0.f;
    if (base) {
        acc0 += base[(size_t)s * bs + w];
        if (w < 24) acc1 += base[(size_t)s * bs + w + 64];
    }
    for (int ww = 0; ww < WIN; ww++) {
        int tg = t0 + q + ww - WSZ;
        if ((unsigned)tg < (unsigned)TLEN) {
            float aw = __shfl(a, ww, 64);
            const float* Rrow = RQ + (size_t)(s + ww - WSZ) * RQs;
            acc0 += aw * Rrow[w];
            if (w < 24) acc1 += aw * Rrow[w + 64];
        }
    }

    float p0 = sigmoid_f(acc0);
    pred_out[(size_t)s * OUTF + w] = p0;
    if (x_out) {
        x_out[(size_t)s * 176 + OUTF + w] = p0;
        x_out[(size_t)s * 176 + w] = feat[(size_t)s * OUTF + w];
    }
    if (w < 24) {
        float p1 = sigmoid_f(acc1);
        pred_out[(size_t)s * OUTF + 64 + w] = p1;
        if (x_out) {
            x_out[(size_t)s * 176 + OUTF + 64 + w] = p1;
            x_out[(size_t)s * 176 + 64 + w] = feat[(size_t)s * OUTF + 64 + w];
        }
    }
}

// ---------------------------------------------------------------------------
extern "C" void kernel_launch(void* const* d_in, const int* in_sizes, int n_in,
                              void* d_out, int out_size, void* d_ws, size_t ws_size,
                              hipStream_t stream)
{
    const float* spec = (const float*)d_in[0];
    const float* Wf   = (const float*)d_in[1];
    const float* bf   = (const float*)d_in[2];
    const float* Wao  = (const float*)d_in[3];
    const float* bao  = (const float*)d_in[4];
    const float* vo   = (const float*)d_in[5];
    const float* Wl1  = (const float*)d_in[6];
    const float* bl1  = (const float*)d_in[7];
    const float* Wac  = (const float*)d_in[8];
    const float* bac  = (const float*)d_in[9];
    const float* vc   = (const float*)d_in[10];
    const float* Wlc  = (const float*)d_in[11];
    const float* blc  = (const float*)d_in[12];

    float* out  = (float*)d_out;
    float* out0 = out;                 // frame_pred [BT,88]
    float* out1 = out + 360448;        // a_frame    [BT,61]
    float* out2 = out + 610304;        // onset_pred [BT,88]
    float* out3 = out + 970752;        // a_onset    [BT,61]
    float* out4 = out + 1220608;       // feat_pred  [BT,88]

    float* ws    = (float*)d_ws;
    float* B2    = ws;                         // 45,056
    float* bias2 = ws + 45056;                 // 256
    float* B1    = ws + 45312;                 // 168,960  (dead after gemm1)
    float* bias1 = ws + 214272;                // 704      (dead after gemm1)
    float* specT = ws + 214976;                // 983,040  (dead after gemm1)
    float* xm    = ws + 45312;                 // 720,896 — aliases B1/bias1/specT
    float* C1    = ws + 1198016;               // 4096*560 = 2,293,760
    float* C2    = ws + 3491776;               // 4096*216 = 884,736 (end 4,376,512)
    (void)ws_size; (void)in_sizes; (void)n_in; (void)out_size;

    // C1 cols [88,648) at stride 560:
    float* h_o = C1;          // +bao folded
    float* P_o = C1 + 128;
    float* P_c = C1 + 256;
    float* Rm  = C1 + 384;
    float* Qm  = C1 + 472;
    // C2: h_c (+bac folded) at 0, linx at 128, stride 216

    pack_kernel<<<(PACK_TOTAL + 255) / 256, 256, 0, stream>>>(
        Wf, bf, Wao, bao, Wl1, Wac, bac, Wlc, B1, B2, bias1, bias2);

    transpose_spec<<<dim3(8, 128), 256, 0, stream>>>(spec, specT);

    gemm_tiled<<<dim3(NP1 / 64, BT / 64), 256, 0, stream>>>(
        nullptr, specT, 0, NBINS, KP1, B1, NP1, bias1, C1, C1LD, NC1, 88, out4);

    attn_v3<<<BT / 8, 512, 0, stream>>>(
        h_o, C1LD, P_o, C1LD, vo, Rm, C1LD, bl1, nullptr, 0,
        out4, out3, out2, xm);

    gemm_tiled<<<dim3(NP2 / 64, BT / 64), 256, 0, stream>>>(
        xm, nullptr, 176, 176, KP2, B2, NP2, bias2, C2, NC2, NC2, 0, nullptr);

    attn_v3<<<BT / 8, 512, 0, stream>>>(
        C2, NC2, P_c, C1LD, vc, Qm, C1LD, blc, C2 + 128, NC2,
        nullptr, out1, out0, nullptr);
}

// Round 4
// 218.812 us; speedup vs baseline: 2.0572x; 1.0050x over previous
//
#include <hip/hip_runtime.h>

#define NBINS 229
#define OUTF  88
#define MODEL 128
#define WSZ   30
#define WIN   61
#define TLEN  1024
#define BT    4096

// packed GEMM geometry
#define NP1 704      // k1 padded N (11*64); real cols 648
#define NC1 648
#define KP1 240      // k1 padded K (15*16); real K 229
#define NP2 256      // k3 padded N; real cols 216
#define NC2 216
#define KP2 176      // k3 K (11*16 exact)
#define C1LD 560     // C1 stores cols [88,648) -> stride 560

__device__ __forceinline__ float tanh_fast(float x) {
    float e = __expf(2.f * x);
    return 1.f - 2.f / (e + 1.f);
}
__device__ __forceinline__ float sigmoid_f(float x) {
    return 1.f / (1.f + __expf(-x));
}

// ---------------------------------------------------------------------------
// prep: pack B1/B2/bias1/bias2 + transpose spec -> specT, one kernel.
// B1[KP1][NP1] column map (n):
//   [  0, 88) Wf[k][n]          [ 88,216) Wao[k][n-88]
//   [216,344) Wao[k+229][n-216] [344,472) Wac[k+176][n-344]
//   [472,560) Wl1[k][n-472]     [560,648) Wlc[k+176][n-560]
// B2[KP2][NP2]: [0,128) Wac[k][n]; [128,216) Wlc[k][n-128]
// bias1: [0,88)=bf, [88,216)=bao, else 0 ; bias2: [0,128)=bac, else 0
// ---------------------------------------------------------------------------
#define B1_ELEMS (KP1 * NP1)
#define B2_ELEMS (KP2 * NP2)
#define PACK_TOTAL (B1_ELEMS + B2_ELEMS + NP1 + NP2)
#define PACK_BLOCKS ((PACK_TOTAL + 255) / 256)
#define TR_BLOCKS (8 * 128)

__global__ __launch_bounds__(256) void prep_kernel(
    const float* __restrict__ Wf,  const float* __restrict__ bf,
    const float* __restrict__ Wao, const float* __restrict__ bao,
    const float* __restrict__ Wl1,
    const float* __restrict__ Wac, const float* __restrict__ bac,
    const float* __restrict__ Wlc,
    const float* __restrict__ spec,
    float* __restrict__ B1, float* __restrict__ B2,
    float* __restrict__ bias1, float* __restrict__ bias2,
    float* __restrict__ specT)
{
    __shared__ float tile[32][33];
    if (blockIdx.x < PACK_BLOCKS) {
        int idx = blockIdx.x * 256 + threadIdx.x;
        if (idx >= PACK_TOTAL) return;
        if (idx < B1_ELEMS) {
            int k = idx / NP1, n = idx % NP1;
            float v = 0.f;
            if (k < NBINS && n < NC1) {
                if (n < 88)       v = Wf[k * 88 + n];
                else if (n < 216) v = Wao[k * MODEL + (n - 88)];
                else if (n < 344) v = Wao[(k + NBINS) * MODEL + (n - 216)];
                else if (n < 472) v = Wac[(k + 176) * MODEL + (n - 344)];
                else if (n < 560) v = Wl1[k * 88 + (n - 472)];
                else              v = Wlc[(k + 176) * 88 + (n - 560)];
            }
            B1[idx] = v;
        } else if (idx < B1_ELEMS + B2_ELEMS) {
            int j = idx - B1_ELEMS;
            int k = j / NP2, n = j % NP2;
            float v = 0.f;
            if (n < 128)      v = Wac[k * MODEL + n];
            else if (n < 216) v = Wlc[k * 88 + (n - 128)];
            B2[j] = v;
        } else if (idx < B1_ELEMS + B2_ELEMS + NP1) {
            int n = idx - (B1_ELEMS + B2_ELEMS);
            bias1[n] = (n < 88) ? bf[n] : (n < 216) ? bao[n - 88] : 0.f;
        } else {
            int n = idx - (B1_ELEMS + B2_ELEMS + NP1);
            bias2[n] = (n < 128) ? bac[n] : 0.f;
        }
    } else {
        int tb = blockIdx.x - PACK_BLOCKS;
        const int k0 = (tb & 7) * 32;
        const int m0 = (tb >> 3) * 32;
        const int x = threadIdx.x & 31, y4 = (threadIdx.x >> 5) * 4;
#pragma unroll
        for (int i = 0; i < 4; i++) {
            int k = k0 + x;
            tile[y4 + i][x] = (k < NBINS) ? spec[(size_t)(m0 + y4 + i) * NBINS + k] : 0.f;
        }
        __syncthreads();
#pragma unroll
        for (int i = 0; i < 4; i++) {
            int k = k0 + y4 + i;
            if (k < KP1) specT[(size_t)k * 4096 + m0 + x] = tile[x][y4 + i];
        }
    }
}

// ---------------------------------------------------------------------------
// Tiled fp32 GEMM with XCD-coherent block swizzle.
// Grid must be (gx, 64) with gx*64 % 8 == 0. Flat dispatch id -> XCD e=flat%8;
// remap so row-tile by covers rows [512e, 512e+512) on XCD e:
//   e = flat&7, k = flat>>3, by = e*8 + (k&7), bx = k>>3.
// C rows [512e,512(e+1)) are then produced AND consumed on XCD e.
// ---------------------------------------------------------------------------
#define KB 16
#define ASTR 68
#define BSTR 64

__global__ __launch_bounds__(256) void gemm_tiled(
    const float* __restrict__ A, const float* __restrict__ AT,
    int lda, int K, int Kpad,
    const float* __restrict__ Bp, int Npad,
    const float* __restrict__ bias,
    float* __restrict__ C, int ldc, int Nc, int cskip,
    float* __restrict__ feat_out)
{
    __shared__ float As[KB * ASTR];
    __shared__ float Bs[KB * BSTR];
    const int tid = threadIdx.x;
    const int tx = tid & 15, ty = tid >> 4;

    const int flat = blockIdx.y * gridDim.x + blockIdx.x;
    const int e = flat & 7, kf = flat >> 3;
    const int rbase = (e * 8 + (kf & 7)) * 64;
    const int cbase = (kf >> 3) * 64;

    float acc[4][4];
#pragma unroll
    for (int i = 0; i < 4; i++)
#pragma unroll
        for (int j = 0; j < 4; j++) acc[i][j] = 0.f;

    const int skk = tid >> 4;            // 0..15 (k within block)
    const int sc4 = (tid & 15) * 4;      // 0..60 (col/row group of 4)
    const int ar = tid >> 2;             // 0..63 row (row-major A path)
    const int akl = tid & 3;             // k lane

    for (int k0 = 0; k0 < Kpad; k0 += KB) {
        if (AT) {
            float4 av = *(const float4*)&AT[(size_t)(k0 + skk) * 4096 + rbase + sc4];
            *(float4*)&As[skk * ASTR + sc4] = av;
        } else {
            const float* arow = A + (size_t)(rbase + ar) * lda;
#pragma unroll
            for (int i = 0; i < 4; i++) {
                int k = k0 + akl + 4 * i;
                As[(akl + 4 * i) * ASTR + ar] = (k < K) ? arow[k] : 0.f;
            }
        }
        {
            float4 bv = *(const float4*)&Bp[(size_t)(k0 + skk) * Npad + cbase + sc4];
            *(float4*)&Bs[skk * BSTR + sc4] = bv;
        }
        __syncthreads();
#pragma unroll
        for (int kk = 0; kk < KB; kk++) {
            float4 av = *(const float4*)&As[kk * ASTR + ty * 4];
            float4 bv = *(const float4*)&Bs[kk * BSTR + tx * 4];
            float a[4] = {av.x, av.y, av.z, av.w};
            float b[4] = {bv.x, bv.y, bv.z, bv.w};
#pragma unroll
            for (int i = 0; i < 4; i++)
#pragma unroll
                for (int j = 0; j < 4; j++) acc[i][j] += a[i] * b[j];
        }
        __syncthreads();
    }

#pragma unroll
    for (int i = 0; i < 4; i++) {
        int r = rbase + ty * 4 + i;
#pragma unroll
        for (int j = 0; j < 4; j++) {
            int c = cbase + tx * 4 + j;
            if (c < Nc) {
                float val = acc[i][j] + bias[c];
                if (c >= cskip) C[(size_t)r * ldc + (c - cskip)] = val;
                if (feat_out && c < 88) feat_out[(size_t)r * 88 + c] = val;
            }
        }
    }
}

// ---------------------------------------------------------------------------
// Attention v4: one wave per position, 8 positions per 512-thread block.
// XCD swizzle: block handles positions in slice [512e, 512(e+1)) matching
// the gemm swizzle -> P/R/h reads hit the home XCD's L2.
// P staged UN-transposed at odd row stride 129 (lane stride 129 % 32 = 1 ->
// 2-way benign). Weighted sum reads R/Q from global (L2-hot post-swizzle).
// ---------------------------------------------------------------------------
#define PST 129

__global__ __launch_bounds__(512) void attn_v4(
    const float* __restrict__ h_all, int hs,
    const float* __restrict__ P_all, int Ps,
    const float* __restrict__ vvec,
    const float* __restrict__ RQ, int RQs,
    const float* __restrict__ pred_bias,
    const float* __restrict__ base, int bs,
    const float* __restrict__ feat,
    float* __restrict__ a_out, float* __restrict__ pred_out,
    float* __restrict__ x_out)
{
    __shared__ float Pl[68 * PST];    // 35,088 B
    __shared__ float Hl[8 * 128];     // 4,096 B
    __shared__ float Vl[128];

    const int tid = threadIdx.x;
    const int e = blockIdx.x & 7;
    const int s0 = (e * 64 + (blockIdx.x >> 3)) * 8;
    const int t0 = s0 & (TLEN - 1);

    if (tid < 128) Vl[tid] = vvec[tid];
    for (int i = tid; i < 8 * 128; i += 512) {
        int q = i >> 7, d = i & 127;
        Hl[i] = h_all[(size_t)(s0 + q) * hs + d];
    }
    // 68 window rows (j=0..67 <-> position s0-30+j)
    for (int i = tid; i < 68 * 128; i += 512) {
        int j = i >> 7, d = i & 127;
        int tg = t0 + j - WSZ;
        float v = 0.f;
        if ((unsigned)tg < (unsigned)TLEN)
            v = P_all[(size_t)(s0 - WSZ + j) * Ps + d];
        Pl[j * PST + d] = v;
    }
    __syncthreads();

    const int q = tid >> 6;           // position within block (wave id)
    const int w = tid & 63;           // lane = window index
    const int s = s0 + q;
    const int row = q + ((w < WIN) ? w : 0);
    const float* pb = &Pl[row * PST];
    const float4* H4 = (const float4*)(Hl + q * 128);
    const float4* V4 = (const float4*)Vl;

    float e_val = 0.f;
#pragma unroll 8
    for (int d4 = 0; d4 < 32; d4++) {
        float4 h = H4[d4];
        float4 v = V4[d4];
        e_val += tanh_fast(h.x + pb[d4 * 4 + 0]) * v.x;
        e_val += tanh_fast(h.y + pb[d4 * 4 + 1]) * v.y;
        e_val += tanh_fast(h.z + pb[d4 * 4 + 2]) * v.z;
        e_val += tanh_fast(h.w + pb[d4 * 4 + 3]) * v.w;
    }
    if (w >= WIN) e_val = -1e30f;

    // in-wave softmax over 61 windows
    float mx = e_val;
#pragma unroll
    for (int m = 32; m; m >>= 1) mx = fmaxf(mx, __shfl_xor(mx, m, 64));
    float ex = __expf(e_val - mx);
    float sm = ex;
#pragma unroll
    for (int m = 32; m; m >>= 1) sm += __shfl_xor(sm, m, 64);
    float a = ex / sm;
    if (w < WIN) a_out[(size_t)s * WIN + w] = a;

    // weighted sum: lane = feature (w and w+64); R/Q rows from global (L2)
    float acc0 = pred_bias[w];
    float acc1 = (w < 24) ? pred_bias[w + 64] : 0.f;
    if (base) {
        acc0 += base[(size_t)s * bs + w];
        if (w < 24) acc1 += base[(size_t)s * bs + w + 64];
    }
    for (int ww = 0; ww < WIN; ww++) {
        int tg = t0 + q + ww - WSZ;
        if ((unsigned)tg < (unsigned)TLEN) {
            float aw = __shfl(a, ww, 64);
            const float* Rrow = RQ + (size_t)(s + ww - WSZ) * RQs;
            acc0 += aw * Rrow[w];
            if (w < 24) acc1 += aw * Rrow[w + 64];
        }
    }

    float p0 = sigmoid_f(acc0);
    pred_out[(size_t)s * OUTF + w] = p0;
    if (x_out) {
        x_out[(size_t)s * 176 + OUTF + w] = p0;
        x_out[(size_t)s * 176 + w] = feat[(size_t)s * OUTF + w];
    }
    if (w < 24) {
        float p1 = sigmoid_f(acc1);
        pred_out[(size_t)s * OUTF + 64 + w] = p1;
        if (x_out) {
            x_out[(size_t)s * 176 + OUTF + 64 + w] = p1;
            x_out[(size_t)s * 176 + 64 + w] = feat[(size_t)s * OUTF + 64 + w];
        }
    }
}

// ---------------------------------------------------------------------------
extern "C" void kernel_launch(void* const* d_in, const int* in_sizes, int n_in,
                              void* d_out, int out_size, void* d_ws, size_t ws_size,
                              hipStream_t stream)
{
    const float* spec = (const float*)d_in[0];
    const float* Wf   = (const float*)d_in[1];
    const float* bf   = (const float*)d_in[2];
    const float* Wao  = (const float*)d_in[3];
    const float* bao  = (const float*)d_in[4];
    const float* vo   = (const float*)d_in[5];
    const float* Wl1  = (const float*)d_in[6];
    const float* bl1  = (const float*)d_in[7];
    const float* Wac  = (const float*)d_in[8];
    const float* bac  = (const float*)d_in[9];
    const float* vc   = (const float*)d_in[10];
    const float* Wlc  = (const float*)d_in[11];
    const float* blc  = (const float*)d_in[12];

    float* out  = (float*)d_out;
    float* out0 = out;                 // frame_pred [BT,88]
    float* out1 = out + 360448;        // a_frame    [BT,61]
    float* out2 = out + 610304;        // onset_pred [BT,88]
    float* out3 = out + 970752;        // a_onset    [BT,61]
    float* out4 = out + 1220608;       // feat_pred  [BT,88]

    float* ws    = (float*)d_ws;
    float* B2    = ws;                         // 45,056
    float* bias2 = ws + 45056;                 // 256
    float* B1    = ws + 45312;                 // 168,960  (dead after gemm1)
    float* bias1 = ws + 214272;                // 704      (dead after gemm1)
    float* specT = ws + 214976;                // 983,040  (dead after gemm1)
    float* xm    = ws + 45312;                 // 720,896 — aliases B1/bias1/specT
    float* C1    = ws + 1198016;               // 4096*560 = 2,293,760
    float* C2    = ws + 3491776;               // 4096*216 = 884,736 (end 4,376,512)
    (void)ws_size; (void)in_sizes; (void)n_in; (void)out_size;

    // C1 cols [88,648) at stride 560:
    float* h_o = C1;          // +bao folded
    float* P_o = C1 + 128;
    float* P_c = C1 + 256;
    float* Rm  = C1 + 384;
    float* Qm  = C1 + 472;
    // C2: h_c (+bac folded) at 0, linx at 128, stride 216

    prep_kernel<<<PACK_BLOCKS + TR_BLOCKS, 256, 0, stream>>>(
        Wf, bf, Wao, bao, Wl1, Wac, bac, Wlc, spec,
        B1, B2, bias1, bias2, specT);

    gemm_tiled<<<dim3(NP1 / 64, BT / 64), 256, 0, stream>>>(
        nullptr, specT, 0, NBINS, KP1, B1, NP1, bias1, C1, C1LD, NC1, 88, out4);

    attn_v4<<<BT / 8, 512, 0, stream>>>(
        h_o, C1LD, P_o, C1LD, vo, Rm, C1LD, bl1, nullptr, 0,
        out4, out3, out2, xm);

    gemm_tiled<<<dim3(NP2 / 64, BT / 64), 256, 0, stream>>>(
        xm, nullptr, 176, 176, KP2, B2, NP2, bias2, C2, NC2, NC2, 0, nullptr);

    attn_v4<<<BT / 8, 512, 0, stream>>>(
        C2, NC2, P_c, C1LD, vc, Qm, C1LD, blc, C2 + 128, NC2,
        nullptr, out1, out0, nullptr);
}

// Round 5
// 188.490 us; speedup vs baseline: 2.3881x; 1.1609x over previous
//
#include <hip/hip_runtime.h>

#define NBINS 229
#define OUTF  88
#define MODEL 128
#define WSZ   30
#define WIN   61
#define TLEN  1024
#define BT    4096

// packed GEMM geometry
#define NP1 704      // k1 padded N (11*64); real cols 648
#define NC1 648
#define KP1 240      // k1 padded K (15*16); real K 229
#define NP2 256      // k3 padded N; real cols 216
#define NC2 216
#define KP2 176      // k3 K (11*16 exact)
#define C1LD 560     // C1 stores cols [88,648) -> stride 560
#define ESCALE 2.0f  // pre-scale for tanh arg: tanh(x) = 1 - 2*rcp(exp(2x)+1)

__device__ __forceinline__ float sigmoid_f(float x) {
    return __builtin_amdgcn_rcpf(1.f + __expf(-x));
}

// ---------------------------------------------------------------------------
// prep: pack B1/B2/bias1/bias2 + transpose spec -> specT + sv sums.
// B1[KP1][NP1] column map (n):
//   [  0, 88) Wf[k][n]          [ 88,216) Wao[k][n-88]
//   [216,344) Wao[k+229][n-216] [344,472) Wac[k+176][n-344]
//   [472,560) Wl1[k][n-472]     [560,648) Wlc[k+176][n-560]
// B2[KP2][NP2]: [0,128) Wac[k][n]; [128,216) Wlc[k][n-128]
// bias1: [0,88)=bf, [88,216)=bao, else 0 ; bias2: [0,128)=bac, else 0
// sv[0] = sum(vo), sv[1] = sum(vc)
// ---------------------------------------------------------------------------
#define B1_ELEMS (KP1 * NP1)
#define B2_ELEMS (KP2 * NP2)
#define PACK_TOTAL (B1_ELEMS + B2_ELEMS + NP1 + NP2)
#define PACK_BLOCKS ((PACK_TOTAL + 255) / 256)
#define TR_BLOCKS (8 * 128)

__global__ __launch_bounds__(256) void prep_kernel(
    const float* __restrict__ Wf,  const float* __restrict__ bf,
    const float* __restrict__ Wao, const float* __restrict__ bao,
    const float* __restrict__ Wl1,
    const float* __restrict__ Wac, const float* __restrict__ bac,
    const float* __restrict__ Wlc,
    const float* __restrict__ spec,
    const float* __restrict__ vo, const float* __restrict__ vc,
    float* __restrict__ B1, float* __restrict__ B2,
    float* __restrict__ bias1, float* __restrict__ bias2,
    float* __restrict__ specT, float* __restrict__ sv)
{
    __shared__ float tile[32][33];
    if (blockIdx.x < PACK_BLOCKS) {
        int idx = blockIdx.x * 256 + threadIdx.x;
        if (idx >= PACK_TOTAL) return;
        if (idx < B1_ELEMS) {
            int k = idx / NP1, n = idx % NP1;
            float v = 0.f;
            if (k < NBINS && n < NC1) {
                if (n < 88)       v = Wf[k * 88 + n];
                else if (n < 216) v = Wao[k * MODEL + (n - 88)];
                else if (n < 344) v = Wao[(k + NBINS) * MODEL + (n - 216)];
                else if (n < 472) v = Wac[(k + 176) * MODEL + (n - 344)];
                else if (n < 560) v = Wl1[k * 88 + (n - 472)];
                else              v = Wlc[(k + 176) * 88 + (n - 560)];
            }
            B1[idx] = v;
        } else if (idx < B1_ELEMS + B2_ELEMS) {
            int j = idx - B1_ELEMS;
            int k = j / NP2, n = j % NP2;
            float v = 0.f;
            if (n < 128)      v = Wac[k * MODEL + n];
            else if (n < 216) v = Wlc[k * 88 + (n - 128)];
            B2[j] = v;
        } else if (idx < B1_ELEMS + B2_ELEMS + NP1) {
            int n = idx - (B1_ELEMS + B2_ELEMS);
            bias1[n] = (n < 88) ? bf[n] : (n < 216) ? bao[n - 88] : 0.f;
        } else {
            int n = idx - (B1_ELEMS + B2_ELEMS + NP1);
            bias2[n] = (n < 128) ? bac[n] : 0.f;
        }
    } else if (blockIdx.x < PACK_BLOCKS + TR_BLOCKS) {
        int tb = blockIdx.x - PACK_BLOCKS;
        const int k0 = (tb & 7) * 32;
        const int m0 = (tb >> 3) * 32;
        const int x = threadIdx.x & 31, y4 = (threadIdx.x >> 5) * 4;
#pragma unroll
        for (int i = 0; i < 4; i++) {
            int k = k0 + x;
            tile[y4 + i][x] = (k < NBINS) ? spec[(size_t)(m0 + y4 + i) * NBINS + k] : 0.f;
        }
        __syncthreads();
#pragma unroll
        for (int i = 0; i < 4; i++) {
            int k = k0 + y4 + i;
            if (k < KP1) specT[(size_t)k * 4096 + m0 + x] = tile[x][y4 + i];
        }
    } else {
        // sv sums: wave 0/1 -> vo halves, wave 2/3 -> vc halves
        int wid = threadIdx.x >> 6, lane = threadIdx.x & 63;
        const float* vp = (wid < 2) ? vo : vc;
        float val = vp[(wid & 1) * 64 + lane];
#pragma unroll
        for (int m = 32; m; m >>= 1) val += __shfl_xor(val, m, 64);
        if (lane == 0) tile[0][wid] = val;
        __syncthreads();
        if (threadIdx.x == 0) {
            sv[0] = tile[0][0] + tile[0][1];
            sv[1] = tile[0][2] + tile[0][3];
        }
    }
}

// ---------------------------------------------------------------------------
// Tiled fp32 GEMM, 128x64 tile, 256 threads, 8x4 micro-tile, KB=16.
// A from AT[Kpad][4096] (pre-transposed, coalesced). XCD swizzle: grid
// (gx,32), flat%8 = XCD e -> row-tile by = 4e + (k&3) covers rows
// [512e,512e+512) on XCD e; bx = k>>2.
// Epilogue: val = (acc+bias[c]); scaled by ESCALE for c in [sclo,schi);
// c>=cskip -> C[r*ldc + c-cskip]; c<88 -> feat_out[r*88+c] (unscaled) and
// xcopy[c*4096+r] (transposed x for gemm2).
// ---------------------------------------------------------------------------
#define KB 16
#define ASTR 132
#define BSTR 68

__global__ __launch_bounds__(256) void gemm_tiled(
    const float* __restrict__ AT, int Kpad,
    const float* __restrict__ Bp, int Npad,
    const float* __restrict__ bias,
    float* __restrict__ C, int ldc, int Nc, int cskip,
    int sclo, int schi,
    float* __restrict__ feat_out, float* __restrict__ xcopy)
{
    __shared__ float As[KB * ASTR];
    __shared__ float Bs[KB * BSTR];
    const int tid = threadIdx.x;
    const int tx = tid & 15, ty = tid >> 4;

    const int flat = blockIdx.y * gridDim.x + blockIdx.x;
    const int e = flat & 7, kf = flat >> 3;
    const int rbase = (e * 4 + (kf & 3)) * 128;
    const int cbase = (kf >> 2) * 64;

    float acc[8][4];
#pragma unroll
    for (int i = 0; i < 8; i++)
#pragma unroll
        for (int j = 0; j < 4; j++) acc[i][j] = 0.f;

    const int skk = tid >> 4, sc4 = (tid & 15) * 4;

    for (int k0 = 0; k0 < Kpad; k0 += KB) {
#pragma unroll
        for (int rp = 0; rp < 2; rp++) {
            int i = tid + rp * 256;
            int kk = i >> 5, r4 = (i & 31) * 4;
            *(float4*)&As[kk * ASTR + r4] =
                *(const float4*)&AT[(size_t)(k0 + kk) * 4096 + rbase + r4];
        }
        *(float4*)&Bs[skk * BSTR + sc4] =
            *(const float4*)&Bp[(size_t)(k0 + skk) * Npad + cbase + sc4];
        __syncthreads();
#pragma unroll
        for (int kk = 0; kk < KB; kk++) {
            float4 a0 = *(const float4*)&As[kk * ASTR + ty * 8];
            float4 a1 = *(const float4*)&As[kk * ASTR + ty * 8 + 4];
            float4 bv = *(const float4*)&Bs[kk * BSTR + tx * 4];
            float a[8] = {a0.x, a0.y, a0.z, a0.w, a1.x, a1.y, a1.z, a1.w};
            float b[4] = {bv.x, bv.y, bv.z, bv.w};
#pragma unroll
            for (int i = 0; i < 8; i++)
#pragma unroll
                for (int j = 0; j < 4; j++) acc[i][j] += a[i] * b[j];
        }
        __syncthreads();
    }

#pragma unroll
    for (int i = 0; i < 8; i++) {
        int r = rbase + ty * 8 + i;
#pragma unroll
        for (int j = 0; j < 4; j++) {
            int c = cbase + tx * 4 + j;
            if (c < Nc) {
                float val = acc[i][j] + bias[c];
                float sval = (c >= sclo && c < schi) ? val * ESCALE : val;
                if (c >= cskip) C[(size_t)r * ldc + (c - cskip)] = sval;
                if (c < 88 && feat_out) {
                    feat_out[(size_t)r * 88 + c] = val;
                    xcopy[(size_t)c * 4096 + r] = val;
                }
            }
        }
    }
}

// ---------------------------------------------------------------------------
// Attention v5: one wave per position, 8 positions per 512-thread block.
// energy e[w] = sv - 2*sum_d v[d]*rcp(exp(h'[d]+p'[w][d])+1), h',p'
// pre-scaled by 2 in gemm epilogue. P staged in LDS at stride 132
// (16B-aligned, bank-balanced b128 reads). h,v via scalar s_loads
// (uniform pointers). Weighted sum: v_readlane + float2 R loads
// (lane = feature pair 2w,2w+1). XCD swizzle matches gemm.
// ---------------------------------------------------------------------------
#define PST 132

__global__ __launch_bounds__(512) void attn_v5(
    const float* __restrict__ h_all, int hs,
    const float* __restrict__ P_all, int Ps,
    const float* __restrict__ vvec,  const float* __restrict__ svp,
    const float* __restrict__ RQ, int RQs,
    const float* __restrict__ pred_bias,
    const float* __restrict__ base, int bs,
    float* __restrict__ a_out, float* __restrict__ pred_out,
    float* __restrict__ xT)
{
    __shared__ float Pl[68 * PST];    // 35,904 B

    const int tid = threadIdx.x;
    const int e = blockIdx.x & 7;
    const int s0 = (e * 64 + (blockIdx.x >> 3)) * 8;
    const int t0 = s0 & (TLEN - 1);

    // stage 68 window rows (pre-scaled P), float4 coalesced
    for (int i = tid; i < 68 * 32; i += 512) {
        int j = i >> 5, d4 = (i & 31) * 4;
        int tg = t0 + j - WSZ;
        float4 v = {0.f, 0.f, 0.f, 0.f};
        if ((unsigned)tg < (unsigned)TLEN)
            v = *(const float4*)&P_all[(size_t)(s0 - WSZ + j) * Ps + d4];
        *(float4*)&Pl[j * PST + d4] = v;
    }
    __syncthreads();

    const int q = tid >> 6;           // position within block (wave id)
    const int w = tid & 63;           // lane = window index
    const int s = s0 + q;
    const int su = __builtin_amdgcn_readfirstlane(s);
    const int row = q + ((w < WIN) ? w : 0);
    const float* hrow = h_all + (size_t)su * hs;   // uniform -> s_load
    const float* pb = &Pl[row * PST];
    const float sv = svp[0];

    float accr = 0.f;
#pragma unroll
    for (int d4 = 0; d4 < 32; d4++) {
        float4 p = *(const float4*)(pb + d4 * 4);
        float4 hh = *(const float4*)(hrow + d4 * 4);   // scalar loads
        float4 vv = *(const float4*)(vvec + d4 * 4);   // scalar loads
        accr += vv.x * __builtin_amdgcn_rcpf(__expf(hh.x + p.x) + 1.f);
        accr += vv.y * __builtin_amdgcn_rcpf(__expf(hh.y + p.y) + 1.f);
        accr += vv.z * __builtin_amdgcn_rcpf(__expf(hh.z + p.z) + 1.f);
        accr += vv.w * __builtin_amdgcn_rcpf(__expf(hh.w + p.w) + 1.f);
    }
    float eng = sv - 2.f * accr;
    if (w >= WIN) eng = -1e30f;

    // in-wave softmax over 61 windows
    float mx = eng;
#pragma unroll
    for (int m = 32; m; m >>= 1) mx = fmaxf(mx, __shfl_xor(mx, m, 64));
    float ex = __expf(eng - mx);
    float sm = ex;
#pragma unroll
    for (int m = 32; m; m >>= 1) sm += __shfl_xor(sm, m, 64);
    float a = ex * __builtin_amdgcn_rcpf(sm);
    if (w < WIN) a_out[(size_t)s * WIN + w] = a;

    // weighted sum: lane covers features (2w, 2w+1), active w<44
    if (w < 44) {
        const int f = 2 * w;
        float acc0 = pred_bias[f], acc1 = pred_bias[f + 1];
        if (base) {
            acc0 += base[(size_t)s * bs + f];
            acc1 += base[(size_t)s * bs + f + 1];
        }
        const float* Rbase = RQ + (size_t)(s - WSZ) * RQs + f;
        if (t0 >= 32 && t0 <= 984) {
#pragma unroll
            for (int ww = 0; ww < WIN; ww++) {
                float aw = __uint_as_float(
                    __builtin_amdgcn_readlane(__float_as_uint(a), ww));
                float2 rr = *(const float2*)(Rbase + (size_t)ww * RQs);
                acc0 += aw * rr.x;
                acc1 += aw * rr.y;
            }
        } else {
            for (int ww = 0; ww < WIN; ww++) {
                int tg = t0 + q + ww - WSZ;
                if ((unsigned)tg < (unsigned)TLEN) {
                    float aw = __uint_as_float(
                        __builtin_amdgcn_readlane(__float_as_uint(a), ww));
                    float2 rr = *(const float2*)(Rbase + (size_t)ww * RQs);
                    acc0 += aw * rr.x;
                    acc1 += aw * rr.y;
                }
            }
        }
        float p0 = sigmoid_f(acc0);
        float p1 = sigmoid_f(acc1);
        *(float2*)&pred_out[(size_t)s * OUTF + f] = make_float2(p0, p1);
        if (xT) {
            xT[(size_t)(88 + f) * 4096 + s] = p0;
            xT[(size_t)(89 + f) * 4096 + s] = p1;
        }
    }
}

// ---------------------------------------------------------------------------
extern "C" void kernel_launch(void* const* d_in, const int* in_sizes, int n_in,
                              void* d_out, int out_size, void* d_ws, size_t ws_size,
                              hipStream_t stream)
{
    const float* spec = (const float*)d_in[0];
    const float* Wf   = (const float*)d_in[1];
    const float* bf   = (const float*)d_in[2];
    const float* Wao  = (const float*)d_in[3];
    const float* bao  = (const float*)d_in[4];
    const float* vo   = (const float*)d_in[5];
    const float* Wl1  = (const float*)d_in[6];
    const float* bl1  = (const float*)d_in[7];
    const float* Wac  = (const float*)d_in[8];
    const float* bac  = (const float*)d_in[9];
    const float* vc   = (const float*)d_in[10];
    const float* Wlc  = (const float*)d_in[11];
    const float* blc  = (const float*)d_in[12];

    float* out  = (float*)d_out;
    float* out0 = out;                 // frame_pred [BT,88]
    float* out1 = out + 360448;        // a_frame    [BT,61]
    float* out2 = out + 610304;        // onset_pred [BT,88]
    float* out3 = out + 970752;        // a_onset    [BT,61]
    float* out4 = out + 1220608;       // feat_pred  [BT,88]

    float* ws    = (float*)d_ws;
    float* B2    = ws;                  // 45,056
    float* bias2 = ws + 45056;          // 256
    float* sv    = ws + 45312;          // 16
    float* B1    = ws + 45328;          // 168,960      (dead after gemm1)
    float* bias1 = ws + 214288;         // 704+pad      (dead after gemm1)
    float* xT    = ws + 215008;         // 176*4096 = 720,896 (transposed x)
    float* specT = ws + 935904;         // 240*4096 = 983,040 (dead after gemm1)
    float* C2    = ws + 935904;         // 4096*216 = 884,736 — aliases specT
    float* C1    = ws + 1918944;        // 4096*560 = 2,293,760 (end 4,212,704)
    (void)ws_size; (void)in_sizes; (void)n_in; (void)out_size;

    // C1 cols [88,648) at stride 560 (h_o/P_o/P_c pre-scaled by 2):
    float* h_o = C1;          // +bao folded, x2
    float* P_o = C1 + 128;    // x2
    float* P_c = C1 + 256;    // x2
    float* Rm  = C1 + 384;
    float* Qm  = C1 + 472;
    // C2: h_c (+bac folded, x2) at 0, linx at 128, stride 216

    prep_kernel<<<PACK_BLOCKS + TR_BLOCKS + 1, 256, 0, stream>>>(
        Wf, bf, Wao, bao, Wl1, Wac, bac, Wlc, spec, vo, vc,
        B1, B2, bias1, bias2, specT, sv);

    gemm_tiled<<<dim3(NP1 / 64, 32), 256, 0, stream>>>(
        specT, KP1, B1, NP1, bias1, C1, C1LD, NC1, 88, 88, 472, out4, xT);

    attn_v5<<<BT / 8, 512, 0, stream>>>(
        h_o, C1LD, P_o, C1LD, vo, sv, Rm, C1LD, bl1,
        nullptr, 0, out3, out2, xT);

    gemm_tiled<<<dim3(NP2 / 64, 32), 256, 0, stream>>>(
        xT, KP2, B2, NP2, bias2, C2, NC2, NC2, 0, 0, 128, nullptr, nullptr);

    attn_v5<<<BT / 8, 512, 0, stream>>>(
        C2, NC2, P_c, C1LD, vc, sv + 1, Qm, C1LD, blc,
        C2 + 128, NC2, out1, out0, nullptr);
}

// Round 6
// 152.574 us; speedup vs baseline: 2.9503x; 1.2354x over previous
//
#include <hip/hip_runtime.h>

#define NBINS 229
#define OUTF  88
#define MODEL 128
#define WSZ   30
#define WIN   61
#define TLEN  1024
#define BT    4096

#define NC1 648      // gemm1 real cols
#define NP1 704      // gemm1 padded cols (11*64)
#define KP1 256      // gemm1 padded K (8*32); real 229
#define NC2 216      // gemm2 real cols
#define NP2 256      // gemm2 padded cols
#define KP2 192      // gemm2 padded K (6*32); real 176
#define C1LD 560     // C1 stores gemm1 cols [88,648) -> stride 560
#define ESCALE 2.0f  // tanh(x) = 1 - 2*rcp(exp(2x)+1); 2x folded into GEMM

typedef short bf16x8 __attribute__((ext_vector_type(8)));
typedef float f32x4 __attribute__((ext_vector_type(4)));
typedef unsigned short ushort_t;

__device__ __forceinline__ float sigmoid_f(float x) {
    return __builtin_amdgcn_rcpf(1.f + __expf(-x));
}
__device__ __forceinline__ ushort_t f2bf(float f) {
    unsigned u = __float_as_uint(f);
    return (ushort_t)((u + 0x7fffu + ((u >> 16) & 1u)) >> 16);
}

// ---------------------------------------------------------------------------
// prep: build bf16 GEMM operands + fp32 biases + sv sums + xB pad zeros.
// B1b[n][k] (n-major, 704x256) column map (n):
//   [  0, 88) Wf[k][n]          [ 88,216) Wao[k][n-88]
//   [216,344) Wao[k+229][n-216] [344,472) Wac[k+176][n-344]
//   [472,560) Wl1[k][n-472]     [560,648) Wlc[k+176][n-560]
// B2b[n][k] (256x192): [0,128) Wac[k][n]; [128,216) Wlc[k][n-128]
// specB[4096][256] bf16 row-major (k>=229 zero)
// xB[4096][192] bf16: cols 176..191 zeroed here (k-pad for gemm2)
// bias1: [0,88)=bf, [88,216)=bao, else 0 ; bias2: [0,128)=bac, else 0
// sv[0]=sum(vo), sv[1]=sum(vc)
// Block segments: [0,704) B1b | [704,896) B2b | [896,1920) specB(x4)
//                 [1920,2176) xB pad | [2176,2180) bias | 2180 sv
// ---------------------------------------------------------------------------
#define PREP_BLOCKS 2181

__global__ __launch_bounds__(256) void prep_kernel(
    const float* __restrict__ Wf,  const float* __restrict__ bfr,
    const float* __restrict__ Wao, const float* __restrict__ bao,
    const float* __restrict__ Wl1,
    const float* __restrict__ Wac, const float* __restrict__ bac,
    const float* __restrict__ Wlc,
    const float* __restrict__ spec,
    const float* __restrict__ vo, const float* __restrict__ vc,
    ushort_t* __restrict__ B1b, ushort_t* __restrict__ B2b,
    ushort_t* __restrict__ specB, ushort_t* __restrict__ xB,
    float* __restrict__ bias1, float* __restrict__ bias2,
    float* __restrict__ sv)
{
    __shared__ float red[4];
    const int b = blockIdx.x;
    if (b < 704) {                                  // B1b
        int idx = b * 256 + threadIdx.x;
        int n = idx >> 8, k = idx & 255;
        float v = 0.f;
        if (k < NBINS && n < NC1) {
            if (n < 88)       v = Wf[k * 88 + n];
            else if (n < 216) v = Wao[k * MODEL + (n - 88)];
            else if (n < 344) v = Wao[(k + NBINS) * MODEL + (n - 216)];
            else if (n < 472) v = Wac[(k + 176) * MODEL + (n - 344)];
            else if (n < 560) v = Wl1[k * 88 + (n - 472)];
            else              v = Wlc[(k + 176) * 88 + (n - 560)];
        }
        B1b[idx] = f2bf(v);
    } else if (b < 896) {                           // B2b
        int idx = (b - 704) * 256 + threadIdx.x;
        int n = idx / 192, k = idx - n * 192;
        float v = 0.f;
        if (k < 176 && n < NC2)
            v = (n < 128) ? Wac[k * MODEL + n] : Wlc[k * 88 + (n - 128)];
        B2b[idx] = f2bf(v);
    } else if (b < 1920) {                          // specB, 4 elems/thread
        int idx = (b - 896) * 256 + threadIdx.x;
        int r = idx >> 6, k4 = (idx & 63) * 4;
        const float* sp = spec + (size_t)r * NBINS;
        ushort4 o;
        o.x = (k4 + 0 < NBINS) ? f2bf(sp[k4 + 0]) : (ushort_t)0;
        o.y = (k4 + 1 < NBINS) ? f2bf(sp[k4 + 1]) : (ushort_t)0;
        o.z = (k4 + 2 < NBINS) ? f2bf(sp[k4 + 2]) : (ushort_t)0;
        o.w = (k4 + 3 < NBINS) ? f2bf(sp[k4 + 3]) : (ushort_t)0;
        *(ushort4*)&specB[(size_t)r * 256 + k4] = o;
    } else if (b < 2176) {                          // xB pad cols 176..191
        int idx = (b - 1920) * 256 + threadIdx.x;
        int r = idx >> 4, c = 176 + (idx & 15);
        xB[(size_t)r * 192 + c] = 0;
    } else if (b < 2180) {                          // biases
        int idx = (b - 2176) * 256 + threadIdx.x;
        if (idx < 704)
            bias1[idx] = (idx < 88) ? bfr[idx] : (idx < 216 ? bao[idx - 88] : 0.f);
        else if (idx < 960) {
            int n = idx - 704;
            bias2[n] = (n < 128) ? bac[n] : 0.f;
        }
    } else {                                        // sv sums
        int wid = threadIdx.x >> 6, lane = threadIdx.x & 63;
        const float* vp = (wid < 2) ? vo : vc;
        float val = vp[(wid & 1) * 64 + lane];
#pragma unroll
        for (int m = 32; m; m >>= 1) val += __shfl_xor(val, m, 64);
        if (lane == 0) red[wid] = val;
        __syncthreads();
        if (threadIdx.x == 0) {
            sv[0] = red[0] + red[1];
            sv[1] = red[2] + red[3];
        }
    }
}

// ---------------------------------------------------------------------------
// MFMA bf16 GEMM, no LDS: A/B fragments stream from global (L2-resident B).
// Block = 256 thr (4 waves); wave tile = (MT*16)m x 64n; block = (MT*64)m x 64n.
// mfma_f32_16x16x32_bf16 fragments:
//   A[m][k]: lane l holds A[m=l&15][k=(l>>4)*8 + j]  -> b128 from row-major A
//   B[k][n]: lane l holds B[k=(l>>4)*8+j][n=l&15]    -> b128 from n-major Bb
//   D[m][n]: lane l reg r -> D[m=(l>>4)*4+r][n=l&15]
// XCD swizzle: e=flat&7 -> rows [512e,512e+512) on XCD e; RTS=log2(row-tiles
// per slice). Software-pipelined one K-step ahead.
// Epilogue: val=acc+bias[n]; cols [sclo,schi) scaled by ESCALE; n>=cskip ->
// C[m*ldc+n-cskip]; n<cskip -> feat_out fp32 + xb bf16 (gemm1 feat path).
// ---------------------------------------------------------------------------
template<int MT, int KITER, int RTS>
__global__ __launch_bounds__(256) void gemm_mfma(
    const ushort_t* __restrict__ Ab, int lka,
    const ushort_t* __restrict__ Bb,
    const float* __restrict__ bias,
    float* __restrict__ C, int ldc, int Nc, int cskip, int sclo, int schi,
    float* __restrict__ feat_out, ushort_t* __restrict__ xb)
{
    const int tid = threadIdx.x;
    const int wv = tid >> 6, ln = tid & 63;
    const int l15 = ln & 15, qd = ln >> 4;
    const int flat = blockIdx.y * gridDim.x + blockIdx.x;
    const int e = flat & 7, kf = flat >> 3;
    const int rb = (e * (1 << RTS) + (kf & ((1 << RTS) - 1))) * (MT * 64);
    const int cb = (kf >> RTS) * 64;
    const int lkb = KITER * 32;

    const ushort_t* ap[MT];
#pragma unroll
    for (int mt = 0; mt < MT; mt++)
        ap[mt] = Ab + (size_t)(rb + wv * MT * 16 + mt * 16 + l15) * lka + qd * 8;
    const ushort_t* bp[4];
#pragma unroll
    for (int nt = 0; nt < 4; nt++)
        bp[nt] = Bb + (size_t)(cb + nt * 16 + l15) * lkb + qd * 8;

    f32x4 acc[MT][4];
#pragma unroll
    for (int mt = 0; mt < MT; mt++)
#pragma unroll
        for (int nt = 0; nt < 4; nt++)
            acc[mt][nt] = (f32x4){0.f, 0.f, 0.f, 0.f};

    bf16x8 af[MT], bfv[4];
#pragma unroll
    for (int mt = 0; mt < MT; mt++) af[mt] = *(const bf16x8*)ap[mt];
#pragma unroll
    for (int nt = 0; nt < 4; nt++) bfv[nt] = *(const bf16x8*)bp[nt];

    for (int it = 0; it < KITER; it++) {
        bf16x8 an[MT], bn[4];
        const int nk = (it + 1 < KITER) ? (it + 1) * 32 : 0;
#pragma unroll
        for (int mt = 0; mt < MT; mt++) an[mt] = *(const bf16x8*)(ap[mt] + nk);
#pragma unroll
        for (int nt = 0; nt < 4; nt++) bn[nt] = *(const bf16x8*)(bp[nt] + nk);
#pragma unroll
        for (int mt = 0; mt < MT; mt++)
#pragma unroll
            for (int nt = 0; nt < 4; nt++)
                acc[mt][nt] = __builtin_amdgcn_mfma_f32_16x16x32_bf16(
                    af[mt], bfv[nt], acc[mt][nt], 0, 0, 0);
#pragma unroll
        for (int mt = 0; mt < MT; mt++) af[mt] = an[mt];
#pragma unroll
        for (int nt = 0; nt < 4; nt++) bfv[nt] = bn[nt];
    }

#pragma unroll
    for (int mt = 0; mt < MT; mt++) {
        const int mbase = rb + wv * MT * 16 + mt * 16 + qd * 4;
#pragma unroll
        for (int nt = 0; nt < 4; nt++) {
            const int n = cb + nt * 16 + l15;
            if (n < Nc) {
                const float bn = bias[n];
                const bool sc = (n >= sclo && n < schi);
#pragma unroll
                for (int r = 0; r < 4; r++) {
                    const int m = mbase + r;
                    float val = acc[mt][nt][r] + bn;
                    float sval = sc ? val * ESCALE : val;
                    if (n >= cskip) {
                        C[(size_t)m * ldc + (n - cskip)] = sval;
                    } else {
                        feat_out[(size_t)m * 88 + n] = val;
                        xb[(size_t)m * 192 + n] = f2bf(val);
                    }
                }
            }
        }
    }
}

// ---------------------------------------------------------------------------
// Attention v6 (= v5 + bf16 x-output): one wave per position, 8 per block.
// energy e[w] = sv - 2*sum_d v[d]*rcp(exp(h'[d]+p'[w][d])+1); h',p' pre-scaled
// by 2 in the GEMM epilogue. P staged in LDS at stride 132; h,v via uniform
// s_loads; in-wave softmax; weighted sum via v_readlane + float2 R loads.
// ---------------------------------------------------------------------------
#define PST 132

__global__ __launch_bounds__(512) void attn_v6(
    const float* __restrict__ h_all, int hs,
    const float* __restrict__ P_all, int Ps,
    const float* __restrict__ vvec,  const float* __restrict__ svp,
    const float* __restrict__ RQ, int RQs,
    const float* __restrict__ pred_bias,
    const float* __restrict__ base, int bs,
    float* __restrict__ a_out, float* __restrict__ pred_out,
    ushort_t* __restrict__ xb)
{
    __shared__ float Pl[68 * PST];

    const int tid = threadIdx.x;
    const int e = blockIdx.x & 7;
    const int s0 = (e * 64 + (blockIdx.x >> 3)) * 8;
    const int t0 = s0 & (TLEN - 1);

    for (int i = tid; i < 68 * 32; i += 512) {
        int j = i >> 5, d4 = (i & 31) * 4;
        int tg = t0 + j - WSZ;
        float4 v = {0.f, 0.f, 0.f, 0.f};
        if ((unsigned)tg < (unsigned)TLEN)
            v = *(const float4*)&P_all[(size_t)(s0 - WSZ + j) * Ps + d4];
        *(float4*)&Pl[j * PST + d4] = v;
    }
    __syncthreads();

    const int q = tid >> 6;
    const int w = tid & 63;
    const int s = s0 + q;
    const int su = __builtin_amdgcn_readfirstlane(s);
    const int row = q + ((w < WIN) ? w : 0);
    const float* hrow = h_all + (size_t)su * hs;
    const float* pb = &Pl[row * PST];
    const float sv = svp[0];

    float accr = 0.f;
#pragma unroll
    for (int d4 = 0; d4 < 32; d4++) {
        float4 p  = *(const float4*)(pb + d4 * 4);
        float4 hh = *(const float4*)(hrow + d4 * 4);
        float4 vv = *(const float4*)(vvec + d4 * 4);
        accr += vv.x * __builtin_amdgcn_rcpf(__expf(hh.x + p.x) + 1.f);
        accr += vv.y * __builtin_amdgcn_rcpf(__expf(hh.y + p.y) + 1.f);
        accr += vv.z * __builtin_amdgcn_rcpf(__expf(hh.z + p.z) + 1.f);
        accr += vv.w * __builtin_amdgcn_rcpf(__expf(hh.w + p.w) + 1.f);
    }
    float eng = sv - 2.f * accr;
    if (w >= WIN) eng = -1e30f;

    float mx = eng;
#pragma unroll
    for (int m = 32; m; m >>= 1) mx = fmaxf(mx, __shfl_xor(mx, m, 64));
    float ex = __expf(eng - mx);
    float sm = ex;
#pragma unroll
    for (int m = 32; m; m >>= 1) sm += __shfl_xor(sm, m, 64);
    float a = ex * __builtin_amdgcn_rcpf(sm);
    if (w < WIN) a_out[(size_t)s * WIN + w] = a;

    if (w < 44) {
        const int f = 2 * w;
        float acc0 = pred_bias[f], acc1 = pred_bias[f + 1];
        if (base) {
            acc0 += base[(size_t)s * bs + f];
            acc1 += base[(size_t)s * bs + f + 1];
        }
        const float* Rbase = RQ + (size_t)(s - WSZ) * RQs + f;
        if (t0 >= 32 && t0 <= 984) {
#pragma unroll
            for (int ww = 0; ww < WIN; ww++) {
                float aw = __uint_as_float(
                    __builtin_amdgcn_readlane(__float_as_uint(a), ww));
                float2 rr = *(const float2*)(Rbase + (size_t)ww * RQs);
                acc0 += aw * rr.x;
                acc1 += aw * rr.y;
            }
        } else {
            for (int ww = 0; ww < WIN; ww++) {
                int tg = t0 + q + ww - WSZ;
                if ((unsigned)tg < (unsigned)TLEN) {
                    float aw = __uint_as_float(
                        __builtin_amdgcn_readlane(__float_as_uint(a), ww));
                    float2 rr = *(const float2*)(Rbase + (size_t)ww * RQs);
                    acc0 += aw * rr.x;
                    acc1 += aw * rr.y;
                }
            }
        }
        float p0 = sigmoid_f(acc0);
        float p1 = sigmoid_f(acc1);
        *(float2*)&pred_out[(size_t)s * OUTF + f] = make_float2(p0, p1);
        if (xb) {
            ushort2 o; o.x = f2bf(p0); o.y = f2bf(p1);
            *(ushort2*)&xb[(size_t)s * 192 + 88 + f] = o;
        }
    }
}

// ---------------------------------------------------------------------------
extern "C" void kernel_launch(void* const* d_in, const int* in_sizes, int n_in,
                              void* d_out, int out_size, void* d_ws, size_t ws_size,
                              hipStream_t stream)
{
    const float* spec = (const float*)d_in[0];
    const float* Wf   = (const float*)d_in[1];
    const float* bf_  = (const float*)d_in[2];
    const float* Wao  = (const float*)d_in[3];
    const float* bao  = (const float*)d_in[4];
    const float* vo   = (const float*)d_in[5];
    const float* Wl1  = (const float*)d_in[6];
    const float* bl1  = (const float*)d_in[7];
    const float* Wac  = (const float*)d_in[8];
    const float* bac  = (const float*)d_in[9];
    const float* vc   = (const float*)d_in[10];
    const float* Wlc  = (const float*)d_in[11];
    const float* blc  = (const float*)d_in[12];

    float* out  = (float*)d_out;
    float* out0 = out;                 // frame_pred [BT,88]
    float* out1 = out + 360448;        // a_frame    [BT,61]
    float* out2 = out + 610304;        // onset_pred [BT,88]
    float* out3 = out + 970752;        // a_onset    [BT,61]
    float* out4 = out + 1220608;       // feat_pred  [BT,88]

    float* ws = (float*)d_ws;
    float*    sv    = ws;                          // 2 (pad 16)
    float*    bias1 = ws + 16;                     // 704
    float*    bias2 = ws + 720;                    // 256
    ushort_t* B1b   = (ushort_t*)(ws + 976);       // 704*256 u16 = 90112 f
    ushort_t* B2b   = (ushort_t*)(ws + 91088);     // 256*192 u16 = 24576 f
    ushort_t* specB = (ushort_t*)(ws + 115664);    // 4096*256 u16 = 524288 f
    ushort_t* xB    = (ushort_t*)(ws + 639952);    // 4096*192 u16 = 393216 f
    float*    C1    = ws + 1033168;                // 4096*560
    float*    C2    = ws + 3326928;                // 4096*216 (end 4,211,664)
    (void)ws_size; (void)in_sizes; (void)n_in; (void)out_size;

    // C1 cols [88,648) at stride 560 (h_o/P_o/P_c pre-scaled by 2):
    float* h_o = C1;          // +bao folded, x2
    float* P_o = C1 + 128;    // x2
    float* P_c = C1 + 256;    // x2
    float* Rm  = C1 + 384;
    float* Qm  = C1 + 472;
    // C2: h_c (+bac folded, x2) at cols 0..127, linx at 128..215, stride 216

    prep_kernel<<<PREP_BLOCKS, 256, 0, stream>>>(
        Wf, bf_, Wao, bao, Wl1, Wac, bac, Wlc, spec, vo, vc,
        B1b, B2b, specB, xB, bias1, bias2, sv);

    gemm_mfma<2, 8, 2><<<dim3(NP1 / 64, 32), 256, 0, stream>>>(
        specB, 256, B1b, bias1, C1, C1LD, NC1, 88, 88, 472, out4, xB);

    attn_v6<<<BT / 8, 512, 0, stream>>>(
        h_o, C1LD, P_o, C1LD, vo, sv, Rm, C1LD, bl1,
        nullptr, 0, out3, out2, xB);

    gemm_mfma<1, 6, 3><<<dim3(NP2 / 64, 64), 256, 0, stream>>>(
        xB, 192, B2b, bias2, C2, NC2, NC2, 0, 0, 128, nullptr, nullptr);

    attn_v6<<<BT / 8, 512, 0, stream>>>(
        C2, NC2, P_c, C1LD, vc, sv + 1, Qm, C1LD, blc,
        C2 + 128, NC2, out1, out0, nullptr);
}

// Round 7
// 146.225 us; speedup vs baseline: 3.0784x; 1.0434x over previous
//
#include <hip/hip_runtime.h>

#define NBINS 229
#define OUTF  88
#define MODEL 128
#define WSZ   30
#define WIN   61
#define TLEN  1024
#define BT    4096

#define NC1 648      // gemm1 real cols
#define NP1 704      // gemm1 padded cols (11*64)
#define KP1 256      // gemm1 padded K (8*32); real 229
#define NC2 216      // gemm2 real cols
#define NP2 256      // gemm2 padded cols
#define KP2 192      // gemm2 padded K (6*32); real 176
#define C1LD 560     // C1 stores gemm1 cols [88,648) -> stride 560

typedef short bf16x8 __attribute__((ext_vector_type(8)));
typedef float f32x4 __attribute__((ext_vector_type(4)));
typedef unsigned short ushort_t;

__device__ __forceinline__ float sigmoid_f(float x) {
    return __builtin_amdgcn_rcpf(1.f + __expf(-x));
}
__device__ __forceinline__ ushort_t f2bf(float f) {
    unsigned u = __float_as_uint(f);
    return (ushort_t)((u + 0x7fffu + ((u >> 16) & 1u)) >> 16);
}

// ---------------------------------------------------------------------------
// prep: build bf16 GEMM operands + fp32 biases + sv sums + xB pad zeros.
// B1b[n][k] (n-major, 704x256) column map (n):
//   [  0, 88) Wf[k][n]          [ 88,216) Wao[k][n-88]
//   [216,344) Wao[k+229][n-216] [344,472) Wac[k+176][n-344]
//   [472,560) Wl1[k][n-472]     [560,648) Wlc[k+176][n-560]
// B2b[n][k] (256x192): [0,128) Wac[k][n]; [128,216) Wlc[k][n-128]
// specB[4096][256] bf16 row-major (k>=229 zero)
// xB[4096][192] bf16: cols 176..191 zeroed here (k-pad for gemm2)
// bias1: [0,88)=bf, [88,216)=bao, else 0 ; bias2: [0,128)=bac, else 0
// sv[0]=sum(vo), sv[1]=sum(vc)
// ---------------------------------------------------------------------------
#define PREP_BLOCKS 2181

__global__ __launch_bounds__(256) void prep_kernel(
    const float* __restrict__ Wf,  const float* __restrict__ bfr,
    const float* __restrict__ Wao, const float* __restrict__ bao,
    const float* __restrict__ Wl1,
    const float* __restrict__ Wac, const float* __restrict__ bac,
    const float* __restrict__ Wlc,
    const float* __restrict__ spec,
    const float* __restrict__ vo, const float* __restrict__ vc,
    ushort_t* __restrict__ B1b, ushort_t* __restrict__ B2b,
    ushort_t* __restrict__ specB, ushort_t* __restrict__ xB,
    float* __restrict__ bias1, float* __restrict__ bias2,
    float* __restrict__ sv)
{
    __shared__ float red[4];
    const int b = blockIdx.x;
    if (b < 704) {                                  // B1b
        int idx = b * 256 + threadIdx.x;
        int n = idx >> 8, k = idx & 255;
        float v = 0.f;
        if (k < NBINS && n < NC1) {
            if (n < 88)       v = Wf[k * 88 + n];
            else if (n < 216) v = Wao[k * MODEL + (n - 88)];
            else if (n < 344) v = Wao[(k + NBINS) * MODEL + (n - 216)];
            else if (n < 472) v = Wac[(k + 176) * MODEL + (n - 344)];
            else if (n < 560) v = Wl1[k * 88 + (n - 472)];
            else              v = Wlc[(k + 176) * 88 + (n - 560)];
        }
        B1b[idx] = f2bf(v);
    } else if (b < 896) {                           // B2b
        int idx = (b - 704) * 256 + threadIdx.x;
        int n = idx / 192, k = idx - n * 192;
        float v = 0.f;
        if (k < 176 && n < NC2)
            v = (n < 128) ? Wac[k * MODEL + n] : Wlc[k * 88 + (n - 128)];
        B2b[idx] = f2bf(v);
    } else if (b < 1920) {                          // specB, 4 elems/thread
        int idx = (b - 896) * 256 + threadIdx.x;
        int r = idx >> 6, k4 = (idx & 63) * 4;
        const float* sp = spec + (size_t)r * NBINS;
        ushort4 o;
        o.x = (k4 + 0 < NBINS) ? f2bf(sp[k4 + 0]) : (ushort_t)0;
        o.y = (k4 + 1 < NBINS) ? f2bf(sp[k4 + 1]) : (ushort_t)0;
        o.z = (k4 + 2 < NBINS) ? f2bf(sp[k4 + 2]) : (ushort_t)0;
        o.w = (k4 + 3 < NBINS) ? f2bf(sp[k4 + 3]) : (ushort_t)0;
        *(ushort4*)&specB[(size_t)r * 256 + k4] = o;
    } else if (b < 2176) {                          // xB pad cols 176..191
        int idx = (b - 1920) * 256 + threadIdx.x;
        int r = idx >> 4, c = 176 + (idx & 15);
        xB[(size_t)r * 192 + c] = 0;
    } else if (b < 2180) {                          // biases
        int idx = (b - 2176) * 256 + threadIdx.x;
        if (idx < 704)
            bias1[idx] = (idx < 88) ? bfr[idx] : (idx < 216 ? bao[idx - 88] : 0.f);
        else if (idx < 960) {
            int n = idx - 704;
            bias2[n] = (n < 128) ? bac[n] : 0.f;
        }
    } else {                                        // sv sums
        int wid = threadIdx.x >> 6, lane = threadIdx.x & 63;
        const float* vp = (wid < 2) ? vo : vc;
        float val = vp[(wid & 1) * 64 + lane];
#pragma unroll
        for (int m = 32; m; m >>= 1) val += __shfl_xor(val, m, 64);
        if (lane == 0) red[wid] = val;
        __syncthreads();
        if (threadIdx.x == 0) {
            sv[0] = red[0] + red[1];
            sv[1] = red[2] + red[3];
        }
    }
}

// ---------------------------------------------------------------------------
// MFMA bf16 GEMM, no LDS: A/B fragments stream from global (L2-resident B).
// Block = 256 thr (4 waves); wave tile = (MT*16)m x 64n.
// XCD swizzle: e=flat&7 -> rows [512e,512e+512) on XCD e.
// Epilogue: val=acc+bias[n]; cols [sclo,schi) -> EXP-transform exp(2*val)
// (pre-factored attention energies: exp(h+p)=exp(h)*exp(p)); n>=cskip ->
// C[m*ldc+n-cskip]; n<cskip -> feat_out fp32 + xb bf16 (gemm1 feat path).
// ---------------------------------------------------------------------------
template<int MT, int KITER, int RTS>
__global__ __launch_bounds__(256) void gemm_mfma(
    const ushort_t* __restrict__ Ab, int lka,
    const ushort_t* __restrict__ Bb,
    const float* __restrict__ bias,
    float* __restrict__ C, int ldc, int Nc, int cskip, int sclo, int schi,
    float* __restrict__ feat_out, ushort_t* __restrict__ xb)
{
    const int tid = threadIdx.x;
    const int wv = tid >> 6, ln = tid & 63;
    const int l15 = ln & 15, qd = ln >> 4;
    const int flat = blockIdx.y * gridDim.x + blockIdx.x;
    const int e = flat & 7, kf = flat >> 3;
    const int rb = (e * (1 << RTS) + (kf & ((1 << RTS) - 1))) * (MT * 64);
    const int cb = (kf >> RTS) * 64;
    const int lkb = KITER * 32;

    const ushort_t* ap[MT];
#pragma unroll
    for (int mt = 0; mt < MT; mt++)
        ap[mt] = Ab + (size_t)(rb + wv * MT * 16 + mt * 16 + l15) * lka + qd * 8;
    const ushort_t* bp[4];
#pragma unroll
    for (int nt = 0; nt < 4; nt++)
        bp[nt] = Bb + (size_t)(cb + nt * 16 + l15) * lkb + qd * 8;

    f32x4 acc[MT][4];
#pragma unroll
    for (int mt = 0; mt < MT; mt++)
#pragma unroll
        for (int nt = 0; nt < 4; nt++)
            acc[mt][nt] = (f32x4){0.f, 0.f, 0.f, 0.f};

    bf16x8 af[MT], bfv[4];
#pragma unroll
    for (int mt = 0; mt < MT; mt++) af[mt] = *(const bf16x8*)ap[mt];
#pragma unroll
    for (int nt = 0; nt < 4; nt++) bfv[nt] = *(const bf16x8*)bp[nt];

    for (int it = 0; it < KITER; it++) {
        bf16x8 an[MT], bn[4];
        const int nk = (it + 1 < KITER) ? (it + 1) * 32 : 0;
#pragma unroll
        for (int mt = 0; mt < MT; mt++) an[mt] = *(const bf16x8*)(ap[mt] + nk);
#pragma unroll
        for (int nt = 0; nt < 4; nt++) bn[nt] = *(const bf16x8*)(bp[nt] + nk);
#pragma unroll
        for (int mt = 0; mt < MT; mt++)
#pragma unroll
            for (int nt = 0; nt < 4; nt++)
                acc[mt][nt] = __builtin_amdgcn_mfma_f32_16x16x32_bf16(
                    af[mt], bfv[nt], acc[mt][nt], 0, 0, 0);
#pragma unroll
        for (int mt = 0; mt < MT; mt++) af[mt] = an[mt];
#pragma unroll
        for (int nt = 0; nt < 4; nt++) bfv[nt] = bn[nt];
    }

#pragma unroll
    for (int mt = 0; mt < MT; mt++) {
        const int mbase = rb + wv * MT * 16 + mt * 16 + qd * 4;
#pragma unroll
        for (int nt = 0; nt < 4; nt++) {
            const int n = cb + nt * 16 + l15;
            if (n < Nc) {
                const float bn = bias[n];
                const bool sc = (n >= sclo && n < schi);
#pragma unroll
                for (int r = 0; r < 4; r++) {
                    const int m = mbase + r;
                    float val = acc[mt][nt][r] + bn;
                    float sval = sc ? __expf(val + val) : val;
                    if (n >= cskip) {
                        C[(size_t)m * ldc + (n - cskip)] = sval;
                    } else {
                        feat_out[(size_t)m * 88 + n] = val;
                        xb[(size_t)m * 192 + n] = f2bf(val);
                    }
                }
            }
        }
    }
}

// ---------------------------------------------------------------------------
// Attention v7: exp-factored energy. EH=exp(2(h+b)) (global, wave-uniform ->
// s_loads), EP=exp(2p) staged in LDS (PADDED ROWS = 1.0 = exp(0)!).
// e[w] = sv - 2*sum_d v[d]*rcp(EH[d]*EP[w][d] + 1)
// One wave per position, 8 per 512-thread block; in-wave softmax;
// weighted sum via v_readlane + float2 R loads; XCD swizzle matches gemm.
// ---------------------------------------------------------------------------
#define PST 132

__global__ __launch_bounds__(512) void attn_v7(
    const float* __restrict__ EH_all, int hs,
    const float* __restrict__ EP_all, int Ps,
    const float* __restrict__ vvec,  const float* __restrict__ svp,
    const float* __restrict__ RQ, int RQs,
    const float* __restrict__ pred_bias,
    const float* __restrict__ base, int bs,
    float* __restrict__ a_out, float* __restrict__ pred_out,
    ushort_t* __restrict__ xb)
{
    __shared__ float Pl[68 * PST];

    const int tid = threadIdx.x;
    const int e = blockIdx.x & 7;
    const int s0 = (e * 64 + (blockIdx.x >> 3)) * 8;
    const int t0 = s0 & (TLEN - 1);

    for (int i = tid; i < 68 * 32; i += 512) {
        int j = i >> 5, d4 = (i & 31) * 4;
        int tg = t0 + j - WSZ;
        float4 v = {1.f, 1.f, 1.f, 1.f};          // pad = exp(0) = 1
        if ((unsigned)tg < (unsigned)TLEN)
            v = *(const float4*)&EP_all[(size_t)(s0 - WSZ + j) * Ps + d4];
        *(float4*)&Pl[j * PST + d4] = v;
    }
    __syncthreads();

    const int q = tid >> 6;
    const int w = tid & 63;
    const int s = s0 + q;
    const int su = __builtin_amdgcn_readfirstlane(s);
    const int row = q + ((w < WIN) ? w : 0);
    const float* hrow = EH_all + (size_t)su * hs;   // uniform -> s_load
    const float* pb = &Pl[row * PST];
    const float sv = svp[0];

    float accr = 0.f;
#pragma unroll 8
    for (int d4 = 0; d4 < 32; d4++) {
        float4 p  = *(const float4*)(pb + d4 * 4);
        float4 hh = *(const float4*)(hrow + d4 * 4);   // scalar loads
        float4 vv = *(const float4*)(vvec + d4 * 4);   // scalar loads
        accr += vv.x * __builtin_amdgcn_rcpf(__builtin_fmaf(hh.x, p.x, 1.f));
        accr += vv.y * __builtin_amdgcn_rcpf(__builtin_fmaf(hh.y, p.y, 1.f));
        accr += vv.z * __builtin_amdgcn_rcpf(__builtin_fmaf(hh.z, p.z, 1.f));
        accr += vv.w * __builtin_amdgcn_rcpf(__builtin_fmaf(hh.w, p.w, 1.f));
    }
    float eng = sv - 2.f * accr;
    if (w >= WIN) eng = -1e30f;

    float mx = eng;
#pragma unroll
    for (int m = 32; m; m >>= 1) mx = fmaxf(mx, __shfl_xor(mx, m, 64));
    float ex = __expf(eng - mx);
    float sm = ex;
#pragma unroll
    for (int m = 32; m; m >>= 1) sm += __shfl_xor(sm, m, 64);
    float a = ex * __builtin_amdgcn_rcpf(sm);
    if (w < WIN) a_out[(size_t)s * WIN + w] = a;

    if (w < 44) {
        const int f = 2 * w;
        float acc0 = pred_bias[f], acc1 = pred_bias[f + 1];
        if (base) {
            acc0 += base[(size_t)s * bs + f];
            acc1 += base[(size_t)s * bs + f + 1];
        }
        const float* Rbase = RQ + (size_t)(s - WSZ) * RQs + f;
        if (t0 >= 32 && t0 <= 984) {
#pragma unroll
            for (int ww = 0; ww < WIN; ww++) {
                float aw = __uint_as_float(
                    __builtin_amdgcn_readlane(__float_as_uint(a), ww));
                float2 rr = *(const float2*)(Rbase + (size_t)ww * RQs);
                acc0 += aw * rr.x;
                acc1 += aw * rr.y;
            }
        } else {
            for (int ww = 0; ww < WIN; ww++) {
                int tg = t0 + q + ww - WSZ;
                if ((unsigned)tg < (unsigned)TLEN) {
                    float aw = __uint_as_float(
                        __builtin_amdgcn_readlane(__float_as_uint(a), ww));
                    float2 rr = *(const float2*)(Rbase + (size_t)ww * RQs);
                    acc0 += aw * rr.x;
                    acc1 += aw * rr.y;
                }
            }
        }
        float p0 = sigmoid_f(acc0);
        float p1 = sigmoid_f(acc1);
        *(float2*)&pred_out[(size_t)s * OUTF + f] = make_float2(p0, p1);
        if (xb) {
            ushort2 o; o.x = f2bf(p0); o.y = f2bf(p1);
            *(ushort2*)&xb[(size_t)s * 192 + 88 + f] = o;
        }
    }
}

// ---------------------------------------------------------------------------
extern "C" void kernel_launch(void* const* d_in, const int* in_sizes, int n_in,
                              void* d_out, int out_size, void* d_ws, size_t ws_size,
                              hipStream_t stream)
{
    const float* spec = (const float*)d_in[0];
    const float* Wf   = (const float*)d_in[1];
    const float* bf_  = (const float*)d_in[2];
    const float* Wao  = (const float*)d_in[3];
    const float* bao  = (const float*)d_in[4];
    const float* vo   = (const float*)d_in[5];
    const float* Wl1  = (const float*)d_in[6];
    const float* bl1  = (const float*)d_in[7];
    const float* Wac  = (const float*)d_in[8];
    const float* bac  = (const float*)d_in[9];
    const float* vc   = (const float*)d_in[10];
    const float* Wlc  = (const float*)d_in[11];
    const float* blc  = (const float*)d_in[12];

    float* out  = (float*)d_out;
    float* out0 = out;                 // frame_pred [BT,88]
    float* out1 = out + 360448;        // a_frame    [BT,61]
    float* out2 = out + 610304;        // onset_pred [BT,88]
    float* out3 = out + 970752;        // a_onset    [BT,61]
    float* out4 = out + 1220608;       // feat_pred  [BT,88]

    float* ws = (float*)d_ws;
    float*    sv    = ws;                          // 2 (pad 16)
    float*    bias1 = ws + 16;                     // 704
    float*    bias2 = ws + 720;                    // 256
    ushort_t* B1b   = (ushort_t*)(ws + 976);       // 704*256 u16
    ushort_t* B2b   = (ushort_t*)(ws + 91088);     // 256*192 u16
    ushort_t* specB = (ushort_t*)(ws + 115664);    // 4096*256 u16
    ushort_t* xB    = (ushort_t*)(ws + 639952);    // 4096*192 u16
    float*    C1    = ws + 1033168;                // 4096*560
    float*    C2    = ws + 3326928;                // 4096*216
    (void)ws_size; (void)in_sizes; (void)n_in; (void)out_size;

    // C1 cols [88,648) at stride 560; h_o/P_o/P_c are EXP'd in epilogue:
    float* h_o = C1;          // exp(2(h+bao))
    float* P_o = C1 + 128;    // exp(2p)
    float* P_c = C1 + 256;    // exp(2p)
    float* Rm  = C1 + 384;
    float* Qm  = C1 + 472;
    // C2: h_c = exp(2(h+bac)) at cols 0..127, linx at 128..215, stride 216

    prep_kernel<<<PREP_BLOCKS, 256, 0, stream>>>(
        Wf, bf_, Wao, bao, Wl1, Wac, bac, Wlc, spec, vo, vc,
        B1b, B2b, specB, xB, bias1, bias2, sv);

    gemm_mfma<2, 8, 2><<<dim3(NP1 / 64, 32), 256, 0, stream>>>(
        specB, 256, B1b, bias1, C1, C1LD, NC1, 88, 88, 472, out4, xB);

    attn_v7<<<BT / 8, 512, 0, stream>>>(
        h_o, C1LD, P_o, C1LD, vo, sv, Rm, C1LD, bl1,
        nullptr, 0, out3, out2, xB);

    gemm_mfma<1, 6, 3><<<dim3(NP2 / 64, 64), 256, 0, stream>>>(
        xB, 192, B2b, bias2, C2, NC2, NC2, 0, 0, 128, nullptr, nullptr);

    attn_v7<<<BT / 8, 512, 0, stream>>>(
        C2, NC2, P_c, C1LD, vc, sv + 1, Qm, C1LD, blc,
        C2 + 128, NC2, out1, out0, nullptr);
}